// Round 1
// baseline (1022.800 us; speedup 1.0000x reference)
//
#include <hip/hip_runtime.h>
#include <math.h>

#define NN 20000
#define HID 128
#define NH 8
#define HD 16
#define LAPD 16
#define NB 1024
#define NBINS 32
#define MAXDEG 64
#define NE 320000
#define DIN 144

// finite "minus infinity" sentinel: never produces inf/NaN arithmetic,
// exp(x - NEGH) underflows to 0 in hardware. Real scores are |s| < ~1e4.
#define NEGH (-1.0e30f)

// ---------------- MLP: l = relu([X,lap]@W1+b1)@W2+b2, argmax over 1024 (fp32) ---
// layer 2 layout: thread t owns 4 CONSECUTIVE cols 4t..4t+3 -> W2 loads are
// float4 (coalesced 16B/lane), outL stores are float4. 4x fewer VMEM instrs.
__global__ __launch_bounds__(256) void mlp_kernel(
    const float* __restrict__ X, const float* __restrict__ lap,
    const float* __restrict__ W1, const float* __restrict__ b1,
    const float* __restrict__ W2, const float* __restrict__ b2,
    float* __restrict__ outL, int* __restrict__ bidx)
{
    __shared__ __align__(16) float xs[16][DIN];
    __shared__ __align__(16) float hs[16][HID];
    __shared__ float rbv[64];
    __shared__ int   rbi[64];
    const int tid = threadIdx.x;
    const int n0 = blockIdx.x * 16;

    for (int e = tid; e < 16 * DIN; e += 256) {
        int n = e / DIN, k = e - n * DIN;
        float v = (k < HID) ? X[(size_t)(n0 + n) * HID + k]
                            : lap[(size_t)(n0 + n) * LAPD + (k - HID)];
        xs[n][k] = v;
    }
    __syncthreads();

    const int c = tid & 127, ng = tid >> 7;
    float hacc[8];
    {
        float bb = b1[c];
        #pragma unroll
        for (int m = 0; m < 8; m++) hacc[m] = bb;
        for (int k = 0; k < DIN; k += 4) {
            float w0 = W1[(k + 0) * HID + c];
            float w1 = W1[(k + 1) * HID + c];
            float w2 = W1[(k + 2) * HID + c];
            float w3 = W1[(k + 3) * HID + c];
            #pragma unroll
            for (int m = 0; m < 8; m++) {
                float4 xv = *(const float4*)&xs[ng * 8 + m][k];
                hacc[m] = fmaf(xv.x, w0, hacc[m]);
                hacc[m] = fmaf(xv.y, w1, hacc[m]);
                hacc[m] = fmaf(xv.z, w2, hacc[m]);
                hacc[m] = fmaf(xv.w, w3, hacc[m]);
            }
        }
    }
    #pragma unroll
    for (int m = 0; m < 8; m++) hs[ng * 8 + m][c] = fmaxf(hacc[m], 0.0f);
    __syncthreads();

    // layer 2: acc[c][m], c = component of float4 (col 4*tid + c)
    float a0[16], a1[16], a2[16], a3[16];
    #pragma unroll
    for (int m = 0; m < 16; m++) { a0[m] = 0.f; a1[m] = 0.f; a2[m] = 0.f; a3[m] = 0.f; }

    for (int k = 0; k < HID; k += 4) {
        const float4 w0 = *(const float4*)&W2[(size_t)(k + 0) * NB + 4 * tid];
        const float4 w1 = *(const float4*)&W2[(size_t)(k + 1) * NB + 4 * tid];
        const float4 w2 = *(const float4*)&W2[(size_t)(k + 2) * NB + 4 * tid];
        const float4 w3 = *(const float4*)&W2[(size_t)(k + 3) * NB + 4 * tid];
        #pragma unroll
        for (int m = 0; m < 16; m++) {
            const float4 hv = *(const float4*)&hs[m][k];
            a0[m] = fmaf(hv.x, w0.x, fmaf(hv.y, w1.x, fmaf(hv.z, w2.x, fmaf(hv.w, w3.x, a0[m]))));
            a1[m] = fmaf(hv.x, w0.y, fmaf(hv.y, w1.y, fmaf(hv.z, w2.y, fmaf(hv.w, w3.y, a1[m]))));
            a2[m] = fmaf(hv.x, w0.z, fmaf(hv.y, w1.z, fmaf(hv.z, w2.z, fmaf(hv.w, w3.z, a2[m]))));
            a3[m] = fmaf(hv.x, w0.w, fmaf(hv.y, w1.w, fmaf(hv.z, w2.w, fmaf(hv.w, w3.w, a3[m]))));
        }
    }

    const float4 bb4 = *(const float4*)&b2[4 * tid];
    const int lane = tid & 63, wv = tid >> 6;
    const int o0 = 4 * tid;
    for (int m = 0; m < 16; m++) {
        float4 ov;
        ov.x = a0[m] + bb4.x; ov.y = a1[m] + bb4.y;
        ov.z = a2[m] + bb4.z; ov.w = a3[m] + bb4.w;
        *(float4*)&outL[(size_t)(n0 + m) * NB + o0] = ov;
        // local argmax over the 4 ascending cols: strict > keeps lowest index
        float bv = ov.x; int bi = o0;
        if (ov.y > bv) { bv = ov.y; bi = o0 + 1; }
        if (ov.z > bv) { bv = ov.z; bi = o0 + 2; }
        if (ov.w > bv) { bv = ov.w; bi = o0 + 3; }
        #pragma unroll
        for (int off = 1; off < 64; off <<= 1) {
            float ovv = __shfl_xor(bv, off, 64);
            int   oi  = __shfl_xor(bi, off, 64);
            if (ovv > bv || (ovv == bv && oi < bi)) { bv = ovv; bi = oi; }
        }
        if (lane == 0) { rbv[wv * 16 + m] = bv; rbi[wv * 16 + m] = bi; }
    }
    __syncthreads();
    if (tid < 16) {
        float bv = rbv[tid]; int bi = rbi[tid];
        #pragma unroll
        for (int ww = 1; ww < 4; ww++) {
            float ov = rbv[ww * 16 + tid]; int oi = rbi[ww * 16 + tid];
            if (ov > bv || (ov == bv && oi < bi)) { bv = ov; bi = oi; }
        }
        bidx[n0 + tid] = min(max(bi, 0), NB - 1);
    }
}

// ---------------- small utility kernels ----------------------------------------
__global__ void zero_kernel(int* __restrict__ p, int n) {
    int i = blockIdx.x * 256 + threadIdx.x;
    if (i < n) p[i] = 0;
}

__global__ void hist_kernel(const int* __restrict__ bkarr, int* __restrict__ bcnt) {
    int i = blockIdx.x * 256 + threadIdx.x;
    if (i < NN) {
        int b = min(max(bkarr[i], 0), NB - 1);
        atomicAdd(&bcnt[b], 1);
    }
}

__global__ __launch_bounds__(1024) void scan_bucket_kernel(const int* __restrict__ cnt,
        int* __restrict__ off, int* __restrict__ fill) {
    __shared__ int s[1024];
    int t = threadIdx.x;
    int v = cnt[t];
    s[t] = v; __syncthreads();
    for (int o = 1; o < 1024; o <<= 1) {
        int a = (t >= o) ? s[t - o] : 0;
        __syncthreads();
        s[t] += a;
        __syncthreads();
    }
    int excl = s[t] - v;
    off[t] = excl; fill[t] = excl;
    if (t == 1023) off[NB] = s[1023];
}

__global__ __launch_bounds__(1024) void scan_edge_kernel(const int* __restrict__ cnt,
        int* __restrict__ off, int* __restrict__ fill) {
    __shared__ int s[1024];
    const int t = threadIdx.x;
    const int base = t * 20;   // 1024*20 >= 20000
    int loc[20]; int sum = 0;
    #pragma unroll
    for (int k = 0; k < 20; k++) {
        int idx = base + k;
        int v = (idx < NN) ? cnt[idx] : 0;
        loc[k] = sum; sum += v;
    }
    s[t] = sum; __syncthreads();
    for (int o = 1; o < 1024; o <<= 1) {
        int a = (t >= o) ? s[t - o] : 0;
        __syncthreads();
        s[t] += a;
        __syncthreads();
    }
    int pre = s[t] - sum;
    #pragma unroll
    for (int k = 0; k < 20; k++) {
        int idx = base + k;
        if (idx < NN) { int e = pre + loc[k]; off[idx] = e; fill[idx] = e; }
    }
    if (t == 1023) off[NN] = s[1023];
}

__global__ void scatter_bucket_kernel(const int* __restrict__ bkarr,
        int* __restrict__ fill, int* __restrict__ blist) {
    int i = blockIdx.x * 256 + threadIdx.x;
    if (i < NN) {
        int b = min(max(bkarr[i], 0), NB - 1);
        int p = atomicAdd(&fill[b], 1);
        if (p >= 0 && p < NN) blist[p] = i;
    }
}

__global__ void edge_count_kernel(const int* __restrict__ ei, int* __restrict__ ecnt) {
    int e = blockIdx.x * 256 + threadIdx.x;
    if (e < NE) {
        int s = min(max(ei[e], 0), NN - 1);
        atomicAdd(&ecnt[s], 1);
    }
}

__global__ void edge_scatter_kernel(const int* __restrict__ ei,
        int* __restrict__ fill, int* __restrict__ adj) {
    int e = blockIdx.x * 256 + threadIdx.x;
    if (e < NE) {
        int s = min(max(ei[e], 0), NN - 1);
        int d = min(max(ei[NE + e], 0), NN - 1);
        int p = atomicAdd(&fill[s], 1);
        if (p >= 0 && p < NE) adj[p] = d;
    }
}

// ------- attention (one wave per src node) + fused h@W_out+b_out epilogue ------
// Restructured: scoring is candidate-major (lane = candidate), PV accumulation
// is dim-major (lane owns output dims {lane, lane+64}) -> 2 accumulator VGPRs
// instead of 128, coalesced V loads, no 64x33 LDS transpose-reduce.
// __launch_bounds__(64,4) caps VGPRs at 128 -> 4 waves/SIMD residency.
__global__ __launch_bounds__(64, 4) void attn_kernel(
    const float* __restrict__ Q, const float* __restrict__ K, const float* __restrict__ V,
    const float* __restrict__ lap,
    const float* __restrict__ spdb, const float* __restrict__ dse,
    const float* __restrict__ dde, const float* __restrict__ bndr,
    const int* __restrict__ deg,
    const int* __restrict__ bq, const int* __restrict__ bkarr,
    const int* __restrict__ boff, const int* __restrict__ blist,
    const int* __restrict__ eoff, const int* __restrict__ adj,
    const float* __restrict__ Wout, const float* __restrict__ bout,
    float* __restrict__ outH)
{
    __shared__ __align__(16) float qf[128];
    __shared__ float pef[16];
    __shared__ float bnd[32];
    __shared__ int   jls[64];
    __shared__ float wtsT[8][65];   // +1 pad: wtsT[h][c] reads hit 4 distinct banks
    __shared__ float al8[8];
    __shared__ float lsum[8];
    __shared__ float hsm[128];
    __shared__ float spdbs[(NBINS + 1) * NH];   // 264 floats
    __shared__ float ddes[(MAXDEG + 2) * NH];   // 528 floats
    const int i = blockIdx.x;
    const int lane = threadIdx.x;
    const int h0 = lane >> 4;       // head of output dim d0 = lane
    const int h1 = h0 + 4;          // head of output dim d1 = lane + 64

    qf[lane]      = Q[(size_t)i * HID + lane];
    qf[lane + 64] = Q[(size_t)i * HID + 64 + lane];
    if (lane < 16) pef[lane] = lap[(size_t)i * LAPD + lane];
    if (lane < 32) bnd[lane] = bndr[lane];
    for (int e = lane; e < (NBINS + 1) * NH; e += 64) spdbs[e] = spdb[e];
    for (int e = lane; e < (MAXDEG + 2) * NH; e += 64) ddes[e] = dde[e];

    int b = min(max(bq[i], 0), NB - 1);
    int bs = boff[b], be = boff[b + 1];
    bs = min(max(bs, 0), NN); be = min(max(be, bs), NN);
    int es = eoff[i], ee = eoff[i + 1];
    es = min(max(es, 0), NE); ee = min(max(ee, es), NE);
    const int Lb = be - bs;
    const int Ltot = Lb + (ee - es);
    const int degi = min(max(deg[i], 0), MAXDEG + 1);
    __syncthreads();

    float dsrc[8];
    #pragma unroll
    for (int h = 0; h < 8; h++) dsrc[h] = dse[degi * 8 + h];

    float m8[8], l8[8];
    #pragma unroll
    for (int h = 0; h < 8; h++) { m8[h] = NEGH; l8[h] = 0.0f; }
    float acc0 = 0.0f, acc1 = 0.0f;

    for (int t0 = 0; t0 < Ltot; t0 += 64) {
        const int t = t0 + lane;
        int j = 0; bool valid = false;
        if (t < Ltot) {
            if (t < Lb) {
                j = blist[bs + t];
                j = min(max(j, 0), NN - 1);
                valid = (j != i);
            } else {
                const int p = t - Lb;
                j = adj[es + p];
                j = min(max(j, 0), NN - 1);
                valid = (j == i) || (bkarr[j] != b);   // skip edges already in the LSH bucket
                if (valid) {
                    for (int q = 0; q < p; q++)        // drop duplicate edges (keep first)
                        if (adj[es + q] == j) { valid = false; break; }
                }
            }
        }
        jls[lane] = valid ? j : 0;   // row 0 read harmlessly with weight 0

        float s8[8];
        if (valid) {
            const float4* K4 = (const float4*)(K + (size_t)j * HID);
            #pragma unroll
            for (int h = 0; h < 8; h++) {
                float4 k0 = K4[h * 4 + 0], k1 = K4[h * 4 + 1];
                float4 k2 = K4[h * 4 + 2], k3 = K4[h * 4 + 3];
                float4 q0 = *(const float4*)&qf[h * 16 + 0];
                float4 q1 = *(const float4*)&qf[h * 16 + 4];
                float4 q2 = *(const float4*)&qf[h * 16 + 8];
                float4 q3 = *(const float4*)&qf[h * 16 + 12];
                float dot = 0.0f;
                dot = fmaf(q0.x, k0.x, dot); dot = fmaf(q0.y, k0.y, dot);
                dot = fmaf(q0.z, k0.z, dot); dot = fmaf(q0.w, k0.w, dot);
                dot = fmaf(q1.x, k1.x, dot); dot = fmaf(q1.y, k1.y, dot);
                dot = fmaf(q1.z, k1.z, dot); dot = fmaf(q1.w, k1.w, dot);
                dot = fmaf(q2.x, k2.x, dot); dot = fmaf(q2.y, k2.y, dot);
                dot = fmaf(q2.z, k2.z, dot); dot = fmaf(q2.w, k2.w, dot);
                dot = fmaf(q3.x, k3.x, dot); dot = fmaf(q3.y, k3.y, dot);
                dot = fmaf(q3.z, k3.z, dot); dot = fmaf(q3.w, k3.w, dot);
                s8[h] = dot * 0.25f;   // /sqrt(16)
            }
            const float* lj = lap + (size_t)j * LAPD;
            float ss = 0.0f;
            #pragma unroll
            for (int d = 0; d < 16; d++) { float df = pef[d] - lj[d]; ss = fmaf(df, df, ss); }
            float dist = sqrtf(ss);
            int si = 0;
            #pragma unroll
            for (int kb = 0; kb < 32; kb++) si += (bnd[kb] < dist) ? 1 : 0;  // searchsorted left
            const int dj = min(max(deg[j], 0), MAXDEG + 1);
            #pragma unroll
            for (int h = 0; h < 8; h++)
                s8[h] += spdbs[si * 8 + h] + dsrc[h] + ddes[dj * 8 + h];
        } else {
            #pragma unroll
            for (int h = 0; h < 8; h++) s8[h] = NEGH;
        }

        // online softmax bookkeeping. m8/l8/alpha are wave-uniform after reduce.
        float alpha8[8];
        #pragma unroll
        for (int h = 0; h < 8; h++) {
            float cm = s8[h];
            #pragma unroll
            for (int off = 1; off < 64; off <<= 1)
                cm = fmaxf(cm, __shfl_xor(cm, off, 64));
            const float mn = fmaxf(m8[h], cm);
            // no inf anywhere: if m8==mn==NEGH -> exp(0)=1 (empty-so-far chunk);
            // if m8==NEGH, mn real -> exp(-1e30) underflows to 0.
            alpha8[h] = __expf(m8[h] - mn);
            float p = valid ? __expf(s8[h] - mn) : 0.0f;
            float sp = p;
            #pragma unroll
            for (int off = 1; off < 64; off <<= 1)
                sp += __shfl_xor(sp, off, 64);
            l8[h] = l8[h] * alpha8[h] + sp;
            m8[h] = mn;
            wtsT[h][lane] = p;
        }
        if (lane == 0) {
            #pragma unroll
            for (int h = 0; h < 8; h++) al8[h] = alpha8[h];
        }
        __syncthreads();

        // dim-major PV accumulation: coalesced V rows, 2 regs per lane
        acc0 *= al8[h0];
        acc1 *= al8[h1];
        const int rem = Ltot - t0;
        const int nc = (rem >= 64) ? 64 : ((rem + 7) & ~7);  // tail entries have w=0
        #pragma unroll 8
        for (int cc = 0; cc < nc; ++cc) {
            const int jc = __builtin_amdgcn_readfirstlane(jls[cc]);
            const float w0 = wtsT[h0][cc];
            const float w1 = wtsT[h1][cc];
            const float* vr = V + (size_t)jc * HID;
            acc0 = fmaf(w0, vr[lane], acc0);
            acc1 = fmaf(w1, vr[lane + 64], acc1);
        }
        __syncthreads();
    }

    if (lane == 0) {
        #pragma unroll
        for (int h = 0; h < 8; h++) lsum[h] = l8[h];
    }
    __syncthreads();
    const float linv0 = 1.0f / (lsum[h0] + 1e-16f);
    const float linv1 = 1.0f / (lsum[h1] + 1e-16f);
    hsm[lane]      = acc0 * linv0;
    hsm[lane + 64] = acc1 * linv1;
    __syncthreads();

    // fused epilogue: out[i, c] = b_out[c] + sum_k h[k] * W_out[k][c]
    float o0 = bout[lane];
    float o1 = bout[lane + 64];
    for (int k = 0; k < HID; k++) {
        const float hk = hsm[k];
        o0 = fmaf(hk, Wout[k * HID + lane], o0);
        o1 = fmaf(hk, Wout[k * HID + 64 + lane], o1);
    }
    outH[(size_t)i * HID + lane]      = o0;
    outH[(size_t)i * HID + 64 + lane] = o1;
}

// ---------------- launch --------------------------------------------------------
extern "C" void kernel_launch(void* const* d_in, const int* in_sizes, int n_in,
                              void* d_out, int out_size, void* d_ws, size_t ws_size,
                              hipStream_t stream) {
    const float* Q    = (const float*)d_in[0];
    const float* Kx   = (const float*)d_in[1];
    const float* Vx   = (const float*)d_in[2];
    const float* lap  = (const float*)d_in[3];
    const float* Wq1  = (const float*)d_in[4];
    const float* bq1  = (const float*)d_in[5];
    const float* Wq2  = (const float*)d_in[6];
    const float* bq2  = (const float*)d_in[7];
    const float* Wk1  = (const float*)d_in[8];
    const float* bk1  = (const float*)d_in[9];
    const float* Wk2  = (const float*)d_in[10];
    const float* bk2  = (const float*)d_in[11];
    const float* spdb = (const float*)d_in[12];
    const float* dse  = (const float*)d_in[13];
    const float* dde  = (const float*)d_in[14];
    const float* Wout = (const float*)d_in[15];
    const float* bout = (const float*)d_in[16];
    const float* bndr = (const float*)d_in[17];
    const int*   ei   = (const int*)d_in[18];
    const int*   deg  = (const int*)d_in[19];

    float* out   = (float*)d_out;
    float* outH  = out;
    float* outLq = out + (size_t)NN * HID;
    float* outLk = outLq + (size_t)NN * NB;

    // workspace: ~1.69 MB total (keep small — ws_size is unknown)
    int* wsp = (int*)d_ws;
    size_t o = 0;
    auto carve = [&](size_t n_ints) -> int* {
        int* p = wsp + o; o += n_ints; return p;
    };
    int* bcnt  = carve(NB);
    int* boff  = carve(NB + 1);
    int* bfill = carve(NB);
    int* blist = carve(NN);
    int* bqv   = carve(NN);
    int* bkv   = carve(NN);
    int* ecnt  = carve(NN);
    int* eoff  = carve(NN + 1);
    int* efill = carve(NN);
    int* adj   = carve(NE);

    zero_kernel<<<(NB + 255) / 256, 256, 0, stream>>>(bcnt, NB);
    zero_kernel<<<(NN + 255) / 256, 256, 0, stream>>>(ecnt, NN);

    mlp_kernel<<<NN / 16, 256, 0, stream>>>(Q,  lap, Wq1, bq1, Wq2, bq2, outLq, bqv);
    mlp_kernel<<<NN / 16, 256, 0, stream>>>(Kx, lap, Wk1, bk1, Wk2, bk2, outLk, bkv);

    hist_kernel<<<(NN + 255) / 256, 256, 0, stream>>>(bkv, bcnt);
    scan_bucket_kernel<<<1, 1024, 0, stream>>>(bcnt, boff, bfill);
    scatter_bucket_kernel<<<(NN + 255) / 256, 256, 0, stream>>>(bkv, bfill, blist);

    edge_count_kernel<<<(NE + 255) / 256, 256, 0, stream>>>(ei, ecnt);
    scan_edge_kernel<<<1, 1024, 0, stream>>>(ecnt, eoff, efill);
    edge_scatter_kernel<<<(NE + 255) / 256, 256, 0, stream>>>(ei, efill, adj);

    attn_kernel<<<NN, 64, 0, stream>>>(Q, Kx, Vx, lap, spdb, dse, dde, bndr, deg,
                                       bqv, bkv, boff, blist, eoff, adj,
                                       Wout, bout, outH);
}

// Round 2
// 882.638 us; speedup vs baseline: 1.1588x; 1.1588x over previous
//
#include <hip/hip_runtime.h>
#include <math.h>

#define NN 20000
#define HID 128
#define NH 8
#define HD 16
#define LAPD 16
#define NB 1024
#define NBINS 32
#define MAXDEG 64
#define NE 320000
#define DIN 144

// finite "minus infinity" sentinel: never produces inf/NaN arithmetic,
// exp(x - NEGH) underflows to 0 in hardware. Real scores are |s| < ~1e4.
#define NEGH (-1.0e30f)

// ---------------- MLP: l = relu([X,lap]@W1+b1)@W2+b2, argmax over 1024 (fp32) ---
__global__ __launch_bounds__(256) void mlp_kernel(
    const float* __restrict__ X, const float* __restrict__ lap,
    const float* __restrict__ W1, const float* __restrict__ b1,
    const float* __restrict__ W2, const float* __restrict__ b2,
    float* __restrict__ outL, int* __restrict__ bidx)
{
    __shared__ __align__(16) float xs[16][DIN];
    __shared__ __align__(16) float hs[16][HID];
    __shared__ float rbv[64];
    __shared__ int   rbi[64];
    const int tid = threadIdx.x;
    const int n0 = blockIdx.x * 16;

    for (int e = tid; e < 16 * DIN; e += 256) {
        int n = e / DIN, k = e - n * DIN;
        float v = (k < HID) ? X[(size_t)(n0 + n) * HID + k]
                            : lap[(size_t)(n0 + n) * LAPD + (k - HID)];
        xs[n][k] = v;
    }
    __syncthreads();

    const int c = tid & 127, ng = tid >> 7;
    float hacc[8];
    {
        float bb = b1[c];
        #pragma unroll
        for (int m = 0; m < 8; m++) hacc[m] = bb;
        for (int k = 0; k < DIN; k += 4) {
            float w0 = W1[(k + 0) * HID + c];
            float w1 = W1[(k + 1) * HID + c];
            float w2 = W1[(k + 2) * HID + c];
            float w3 = W1[(k + 3) * HID + c];
            #pragma unroll
            for (int m = 0; m < 8; m++) {
                float4 xv = *(const float4*)&xs[ng * 8 + m][k];
                hacc[m] = fmaf(xv.x, w0, hacc[m]);
                hacc[m] = fmaf(xv.y, w1, hacc[m]);
                hacc[m] = fmaf(xv.z, w2, hacc[m]);
                hacc[m] = fmaf(xv.w, w3, hacc[m]);
            }
        }
    }
    #pragma unroll
    for (int m = 0; m < 8; m++) hs[ng * 8 + m][c] = fmaxf(hacc[m], 0.0f);
    __syncthreads();

    float a0[16], a1[16], a2[16], a3[16];
    #pragma unroll
    for (int m = 0; m < 16; m++) { a0[m] = 0.f; a1[m] = 0.f; a2[m] = 0.f; a3[m] = 0.f; }

    for (int k = 0; k < HID; k += 4) {
        const float4 w0 = *(const float4*)&W2[(size_t)(k + 0) * NB + 4 * tid];
        const float4 w1 = *(const float4*)&W2[(size_t)(k + 1) * NB + 4 * tid];
        const float4 w2 = *(const float4*)&W2[(size_t)(k + 2) * NB + 4 * tid];
        const float4 w3 = *(const float4*)&W2[(size_t)(k + 3) * NB + 4 * tid];
        #pragma unroll
        for (int m = 0; m < 16; m++) {
            const float4 hv = *(const float4*)&hs[m][k];
            a0[m] = fmaf(hv.x, w0.x, fmaf(hv.y, w1.x, fmaf(hv.z, w2.x, fmaf(hv.w, w3.x, a0[m]))));
            a1[m] = fmaf(hv.x, w0.y, fmaf(hv.y, w1.y, fmaf(hv.z, w2.y, fmaf(hv.w, w3.y, a1[m]))));
            a2[m] = fmaf(hv.x, w0.z, fmaf(hv.y, w1.z, fmaf(hv.z, w2.z, fmaf(hv.w, w3.z, a2[m]))));
            a3[m] = fmaf(hv.x, w0.w, fmaf(hv.y, w1.w, fmaf(hv.z, w2.w, fmaf(hv.w, w3.w, a3[m]))));
        }
    }

    const float4 bb4 = *(const float4*)&b2[4 * tid];
    const int lane = tid & 63, wv = tid >> 6;
    const int o0 = 4 * tid;
    for (int m = 0; m < 16; m++) {
        float4 ov;
        ov.x = a0[m] + bb4.x; ov.y = a1[m] + bb4.y;
        ov.z = a2[m] + bb4.z; ov.w = a3[m] + bb4.w;
        *(float4*)&outL[(size_t)(n0 + m) * NB + o0] = ov;
        float bv = ov.x; int bi = o0;
        if (ov.y > bv) { bv = ov.y; bi = o0 + 1; }
        if (ov.z > bv) { bv = ov.z; bi = o0 + 2; }
        if (ov.w > bv) { bv = ov.w; bi = o0 + 3; }
        #pragma unroll
        for (int off = 1; off < 64; off <<= 1) {
            float ovv = __shfl_xor(bv, off, 64);
            int   oi  = __shfl_xor(bi, off, 64);
            if (ovv > bv || (ovv == bv && oi < bi)) { bv = ovv; bi = oi; }
        }
        if (lane == 0) { rbv[wv * 16 + m] = bv; rbi[wv * 16 + m] = bi; }
    }
    __syncthreads();
    if (tid < 16) {
        float bv = rbv[tid]; int bi = rbi[tid];
        #pragma unroll
        for (int ww = 1; ww < 4; ww++) {
            float ov = rbv[ww * 16 + tid]; int oi = rbi[ww * 16 + tid];
            if (ov > bv || (ov == bv && oi < bi)) { bv = ov; bi = oi; }
        }
        bidx[n0 + tid] = min(max(bi, 0), NB - 1);
    }
}

// ---------------- small utility kernels ----------------------------------------
__global__ void zero_kernel(int* __restrict__ p, int n) {
    int i = blockIdx.x * 256 + threadIdx.x;
    if (i < n) p[i] = 0;
}

__global__ void hist_kernel(const int* __restrict__ bkarr, int* __restrict__ bcnt) {
    int i = blockIdx.x * 256 + threadIdx.x;
    if (i < NN) {
        int b = min(max(bkarr[i], 0), NB - 1);
        atomicAdd(&bcnt[b], 1);
    }
}

__global__ __launch_bounds__(1024) void scan_bucket_kernel(const int* __restrict__ cnt,
        int* __restrict__ off, int* __restrict__ fill) {
    __shared__ int s[1024];
    int t = threadIdx.x;
    int v = cnt[t];
    s[t] = v; __syncthreads();
    for (int o = 1; o < 1024; o <<= 1) {
        int a = (t >= o) ? s[t - o] : 0;
        __syncthreads();
        s[t] += a;
        __syncthreads();
    }
    int excl = s[t] - v;
    off[t] = excl; fill[t] = excl;
    if (t == 1023) off[NB] = s[1023];
}

__global__ __launch_bounds__(1024) void scan_edge_kernel(const int* __restrict__ cnt,
        int* __restrict__ off, int* __restrict__ fill) {
    __shared__ int s[1024];
    const int t = threadIdx.x;
    const int base = t * 20;   // 1024*20 >= 20000
    int loc[20]; int sum = 0;
    #pragma unroll
    for (int k = 0; k < 20; k++) {
        int idx = base + k;
        int v = (idx < NN) ? cnt[idx] : 0;
        loc[k] = sum; sum += v;
    }
    s[t] = sum; __syncthreads();
    for (int o = 1; o < 1024; o <<= 1) {
        int a = (t >= o) ? s[t - o] : 0;
        __syncthreads();
        s[t] += a;
        __syncthreads();
    }
    int pre = s[t] - sum;
    #pragma unroll
    for (int k = 0; k < 20; k++) {
        int idx = base + k;
        if (idx < NN) { int e = pre + loc[k]; off[idx] = e; fill[idx] = e; }
    }
    if (t == 1023) off[NN] = s[1023];
}

__global__ void scatter_bucket_kernel(const int* __restrict__ bkarr,
        int* __restrict__ fill, int* __restrict__ blist) {
    int i = blockIdx.x * 256 + threadIdx.x;
    if (i < NN) {
        int b = min(max(bkarr[i], 0), NB - 1);
        int p = atomicAdd(&fill[b], 1);
        if (p >= 0 && p < NN) blist[p] = i;
    }
}

__global__ void edge_count_kernel(const int* __restrict__ ei, int* __restrict__ ecnt) {
    int e = blockIdx.x * 256 + threadIdx.x;
    if (e < NE) {
        int s = min(max(ei[e], 0), NN - 1);
        atomicAdd(&ecnt[s], 1);
    }
}

__global__ void edge_scatter_kernel(const int* __restrict__ ei,
        int* __restrict__ fill, int* __restrict__ adj) {
    int e = blockIdx.x * 256 + threadIdx.x;
    if (e < NE) {
        int s = min(max(ei[e], 0), NN - 1);
        int d = min(max(ei[NE + e], 0), NN - 1);
        int p = atomicAdd(&fill[s], 1);
        if (p >= 0 && p < NE) adj[p] = d;
    }
}

// ------- adjacency clean-up (off the hot path): per node, drop edges that are
// already covered by the LSH bucket ((j!=i && bk[j]==bq[i])) and duplicate
// edges (keep first occurrence). Compacts adj in place, writes kept count.
// One wave per node; dup check via shuffles (deg <= 64 in practice).
__global__ __launch_bounds__(256) void dedup_kernel(
    const int* __restrict__ eoff, int* __restrict__ adj,
    const int* __restrict__ bqv, const int* __restrict__ bkv,
    int* __restrict__ acnt)
{
    __shared__ int prev[4][192];
    const int lane = threadIdx.x & 63, wv = threadIdx.x >> 6;
    const int i = blockIdx.x * 4 + wv;
    if (i >= NN) return;
    int es = eoff[i], ee = eoff[i + 1];
    es = min(max(es, 0), NE); ee = min(max(ee, es), NE);
    const int d = ee - es;
    const int b = min(max(bqv[i], 0), NB - 1);
    int kept = 0;
    for (int t0 = 0; t0 < d; t0 += 64) {
        const int t = t0 + lane;
        const bool in = t < d;
        int j = -1;
        if (in) j = min(max(adj[es + t], 0), NN - 1);
        bool keep = in && ((j == i) || (bkv[j] != b));
        // dup vs earlier entries in this chunk (compare vs ALL earlier raw entries)
        const int nin = min(64, d - t0);
        for (int q2 = 0; q2 < nin; q2++) {
            int jq = __shfl(j, q2, 64);
            if (in && q2 < lane && jq == j) keep = false;
        }
        // dup vs earlier chunks (rare: only when d > 64)
        if (t0 > 0 && in) {
            asm volatile("s_waitcnt lgkmcnt(0)" ::: "memory");
            const int np = min(t0, 192);
            for (int q2 = 0; q2 < np; q2++)
                if (prev[wv][q2] == j) keep = false;
        }
        if (in && t < 192) prev[wv][t] = j;   // record ORIGINAL value before compaction
        unsigned long long km = __ballot(keep);
        int pos = __popcll(km & ((1ull << lane) - 1ull));
        if (keep) adj[es + kept + pos] = j;   // write idx <= read idx: in-place safe
        kept += (int)__popcll(km);
    }
    if (lane == 0) acnt[i] = kept;
}

// ------- attention: 4 waves/block, 1 node/wave, bucket-ordered via qlist -------
// Phase A (candidate-major, lane=candidate): K gather + 8-head dots + biases.
// Softmax: per-head wave max; weights -> LDS transpose (same wave, no barrier).
// Phase B (quad-split PV): lane (c=lane>>2, q=lane&3) owns dims q*32..q*32+31
// (heads 2q,2q+1), acc[32] regs, 4 passes x 16 candidates, 128B-contig V reads.
// Final: butterfly-sum acc over c-lanes, fused h@W_out+b_out epilogue.
__global__ __launch_bounds__(256, 3) void attn_kernel(
    const float* __restrict__ Q, const float* __restrict__ K, const float* __restrict__ V,
    const float* __restrict__ lap,
    const float* __restrict__ spdb, const float* __restrict__ dse,
    const float* __restrict__ dde, const float* __restrict__ bndr,
    const int* __restrict__ deg,
    const int* __restrict__ bq,
    const int* __restrict__ boff, const int* __restrict__ blist,
    const int* __restrict__ eoff, const int* __restrict__ acnt,
    const int* __restrict__ adj, const int* __restrict__ qlist,
    const float* __restrict__ Wout, const float* __restrict__ bout,
    float* __restrict__ outH)
{
    __shared__ __align__(16) float qfl[4][128];
    __shared__ __align__(16) float pefl[4][16];
    __shared__ __align__(16) float hsm[4][128];
    __shared__ float wts[4][8][66];
    __shared__ int   jls[4][64];
    __shared__ __align__(16) float spdbs[(NBINS + 1) * NH];   // 264
    __shared__ __align__(16) float ddes[(MAXDEG + 2) * NH];   // 528
    __shared__ float bnd[32];

    const int tid = threadIdx.x;
    const int wv = tid >> 6, lane = tid & 63;
    const int cq = lane >> 2, qq = lane & 3;   // candidate slot / dim-quarter

    // bijective XCD chunking: 5000 blocks = 8 * 625
    int blk = (int)blockIdx.x;
    blk = (blk & 7) * 625 + (blk >> 3);
    const int task = blk * 4 + wv;
    int i = qlist[task];
    i = min(max(i, 0), NN - 1);

    for (int e = tid; e < (NBINS + 1) * NH; e += 256) spdbs[e] = spdb[e];
    for (int e = tid; e < (MAXDEG + 2) * NH; e += 256) ddes[e] = dde[e];
    if (tid < 32) bnd[tid] = bndr[tid];
    qfl[wv][lane]      = Q[(size_t)i * HID + lane];
    qfl[wv][lane + 64] = Q[(size_t)i * HID + 64 + lane];
    if (lane < 16) pefl[wv][lane] = lap[(size_t)i * LAPD + lane];

    int b = min(max(bq[i], 0), NB - 1);
    int bs = boff[b], be = boff[b + 1];
    bs = min(max(bs, 0), NN); be = min(max(be, bs), NN);
    int es = eoff[i];
    es = min(max(es, 0), NE);
    int na = min(max(acnt[i], 0), NE - es);
    const int Lb = be - bs;
    const int Ltot = Lb + na;
    const int degi = min(max(deg[i], 0), MAXDEG + 1);
    __syncthreads();   // tables + per-wave staging visible

    const float4 ds0 = *(const float4*)&dse[degi * 8];
    const float4 ds1 = *(const float4*)&dse[degi * 8 + 4];

    float m8[8], l8[8];
    #pragma unroll
    for (int h = 0; h < 8; h++) { m8[h] = NEGH; l8[h] = 0.0f; }
    float acc[32];
    #pragma unroll
    for (int k = 0; k < 32; k++) acc[k] = 0.0f;

    for (int t0 = 0; t0 < Ltot; t0 += 64) {
        const int t = t0 + lane;
        int j = i; bool valid = false;
        if (t < Ltot) {
            if (t < Lb) {
                j = min(max(blist[bs + t], 0), NN - 1);
                valid = (j != i);
            } else {
                j = min(max(adj[es + (t - Lb)], 0), NN - 1);
                valid = true;   // pre-deduped, pre-filtered
            }
        }

        // ---- phase A: candidate-major scores ----
        float s8[8];
        if (valid) {
            const float4* K4 = (const float4*)(K + (size_t)j * HID);
            const float4* Q4 = (const float4*)&qfl[wv][0];
            #pragma unroll
            for (int h = 0; h < 8; h++) {
                float4 k0 = K4[h * 4 + 0], k1 = K4[h * 4 + 1];
                float4 k2 = K4[h * 4 + 2], k3 = K4[h * 4 + 3];
                float4 q0 = Q4[h * 4 + 0], q1 = Q4[h * 4 + 1];
                float4 q2 = Q4[h * 4 + 2], q3 = Q4[h * 4 + 3];
                float dot = 0.0f;
                dot = fmaf(q0.x, k0.x, dot); dot = fmaf(q0.y, k0.y, dot);
                dot = fmaf(q0.z, k0.z, dot); dot = fmaf(q0.w, k0.w, dot);
                dot = fmaf(q1.x, k1.x, dot); dot = fmaf(q1.y, k1.y, dot);
                dot = fmaf(q1.z, k1.z, dot); dot = fmaf(q1.w, k1.w, dot);
                dot = fmaf(q2.x, k2.x, dot); dot = fmaf(q2.y, k2.y, dot);
                dot = fmaf(q2.z, k2.z, dot); dot = fmaf(q2.w, k2.w, dot);
                dot = fmaf(q3.x, k3.x, dot); dot = fmaf(q3.y, k3.y, dot);
                dot = fmaf(q3.z, k3.z, dot); dot = fmaf(q3.w, k3.w, dot);
                s8[h] = dot * 0.25f;   // /sqrt(16)
            }
            const float4* P4 = (const float4*)&pefl[wv][0];
            const float4* L4 = (const float4*)(lap + (size_t)j * LAPD);
            float ss = 0.0f;
            #pragma unroll
            for (int d4 = 0; d4 < 4; d4++) {
                float4 pe = P4[d4], lj = L4[d4];
                float dx = pe.x - lj.x, dy = pe.y - lj.y;
                float dz = pe.z - lj.z, dw = pe.w - lj.w;
                ss = fmaf(dx, dx, ss); ss = fmaf(dy, dy, ss);
                ss = fmaf(dz, dz, ss); ss = fmaf(dw, dw, ss);
            }
            float dist = sqrtf(ss);
            int si = 0;
            #pragma unroll
            for (int kb = 0; kb < 32; kb++) si += (bnd[kb] < dist) ? 1 : 0;  // searchsorted left
            const int dj = min(max(deg[j], 0), MAXDEG + 1);
            const float4 sb0 = *(const float4*)&spdbs[si * 8];
            const float4 sb1 = *(const float4*)&spdbs[si * 8 + 4];
            const float4 db0 = *(const float4*)&ddes[dj * 8];
            const float4 db1 = *(const float4*)&ddes[dj * 8 + 4];
            s8[0] += sb0.x + ds0.x + db0.x; s8[1] += sb0.y + ds0.y + db0.y;
            s8[2] += sb0.z + ds0.z + db0.z; s8[3] += sb0.w + ds0.w + db0.w;
            s8[4] += sb1.x + ds1.x + db1.x; s8[5] += sb1.y + ds1.y + db1.y;
            s8[6] += sb1.z + ds1.z + db1.z; s8[7] += sb1.w + ds1.w + db1.w;
        } else {
            #pragma unroll
            for (int h = 0; h < 8; h++) s8[h] = NEGH;
        }

        // ---- softmax bookkeeping (m wave-uniform, l per-lane partial) ----
        float alpha8[8];
        #pragma unroll
        for (int h = 0; h < 8; h++) {
            float cm = s8[h];
            #pragma unroll
            for (int off = 1; off < 64; off <<= 1)
                cm = fmaxf(cm, __shfl_xor(cm, off, 64));
            const float mn = fmaxf(m8[h], cm);
            alpha8[h] = __expf(m8[h] - mn);
            const float p = valid ? __expf(s8[h] - mn) : 0.0f;
            l8[h] = l8[h] * alpha8[h] + p;
            m8[h] = mn;
            wts[wv][h][lane] = p;
        }
        jls[wv][lane] = valid ? j : i;

        // alpha for this lane's two heads (compile-time indices per arm)
        float aq0, aq1;
        if (qq == 0)      { aq0 = alpha8[0]; aq1 = alpha8[1]; }
        else if (qq == 1) { aq0 = alpha8[2]; aq1 = alpha8[3]; }
        else if (qq == 2) { aq0 = alpha8[4]; aq1 = alpha8[5]; }
        else              { aq0 = alpha8[6]; aq1 = alpha8[7]; }

        #pragma unroll
        for (int k = 0; k < 16; k++) acc[k] *= aq0;
        #pragma unroll
        for (int k = 16; k < 32; k++) acc[k] *= aq1;

        // same-wave LDS handoff: drain DS writes before cross-lane reads
        asm volatile("s_waitcnt lgkmcnt(0)" ::: "memory");

        // ---- phase B: quad-split PV ----
        const int rem = Ltot - t0;
        const int npass = ((rem < 64 ? rem : 64) + 15) >> 4;
        for (int r = 0; r < npass; r++) {
            const int cc = r * 16 + cq;
            const int jc = jls[wv][cc];
            const float w0 = wts[wv][2 * qq][cc];
            const float w1 = wts[wv][2 * qq + 1][cc];
            const float4* V4 = (const float4*)(V + (size_t)jc * HID + qq * 32);
            #pragma unroll
            for (int s = 0; s < 4; s++) {
                const float4 v = V4[s];
                acc[s * 4 + 0] = fmaf(w0, v.x, acc[s * 4 + 0]);
                acc[s * 4 + 1] = fmaf(w0, v.y, acc[s * 4 + 1]);
                acc[s * 4 + 2] = fmaf(w0, v.z, acc[s * 4 + 2]);
                acc[s * 4 + 3] = fmaf(w0, v.w, acc[s * 4 + 3]);
            }
            #pragma unroll
            for (int s = 4; s < 8; s++) {
                const float4 v = V4[s];
                acc[s * 4 + 0] = fmaf(w1, v.x, acc[s * 4 + 0]);
                acc[s * 4 + 1] = fmaf(w1, v.y, acc[s * 4 + 1]);
                acc[s * 4 + 2] = fmaf(w1, v.z, acc[s * 4 + 2]);
                acc[s * 4 + 3] = fmaf(w1, v.w, acc[s * 4 + 3]);
            }
        }
    }

    // ---- final reduces ----
    #pragma unroll
    for (int h = 0; h < 8; h++) {
        float v = l8[h];
        #pragma unroll
        for (int off = 1; off < 64; off <<= 1) v += __shfl_xor(v, off, 64);
        l8[h] = v;
    }
    float lq0, lq1;
    if (qq == 0)      { lq0 = l8[0]; lq1 = l8[1]; }
    else if (qq == 1) { lq0 = l8[2]; lq1 = l8[3]; }
    else if (qq == 2) { lq0 = l8[4]; lq1 = l8[5]; }
    else              { lq0 = l8[6]; lq1 = l8[7]; }
    const float linv0 = 1.0f / (lq0 + 1e-16f);
    const float linv1 = 1.0f / (lq1 + 1e-16f);
    #pragma unroll
    for (int k = 0; k < 16; k++) acc[k] *= linv0;
    #pragma unroll
    for (int k = 16; k < 32; k++) acc[k] *= linv1;

    // butterfly-sum over the 16 candidate-slot lanes (xor bits 2..5)
    #pragma unroll
    for (int k = 0; k < 32; k++) {
        float v = acc[k];
        v += __shfl_xor(v, 4, 64);
        v += __shfl_xor(v, 8, 64);
        v += __shfl_xor(v, 16, 64);
        v += __shfl_xor(v, 32, 64);
        acc[k] = v;
    }
    if (cq == 0) {   // lanes 0..3; lane qq writes dims qq*32..qq*32+31
        #pragma unroll
        for (int k = 0; k < 32; k++) hsm[wv][qq * 32 + k] = acc[k];
    }
    asm volatile("s_waitcnt lgkmcnt(0)" ::: "memory");

    // fused epilogue: out[i, c] = b_out[c] + sum_k h[k] * W_out[k][c]
    float o0 = bout[lane];
    float o1 = bout[lane + 64];
    for (int k = 0; k < HID; k++) {
        const float hk = hsm[wv][k];
        o0 = fmaf(hk, Wout[k * HID + lane], o0);
        o1 = fmaf(hk, Wout[k * HID + 64 + lane], o1);
    }
    outH[(size_t)i * HID + lane]      = o0;
    outH[(size_t)i * HID + 64 + lane] = o1;
}

// ---------------- launch --------------------------------------------------------
extern "C" void kernel_launch(void* const* d_in, const int* in_sizes, int n_in,
                              void* d_out, int out_size, void* d_ws, size_t ws_size,
                              hipStream_t stream) {
    const float* Q    = (const float*)d_in[0];
    const float* Kx   = (const float*)d_in[1];
    const float* Vx   = (const float*)d_in[2];
    const float* lap  = (const float*)d_in[3];
    const float* Wq1  = (const float*)d_in[4];
    const float* bq1  = (const float*)d_in[5];
    const float* Wq2  = (const float*)d_in[6];
    const float* bq2  = (const float*)d_in[7];
    const float* Wk1  = (const float*)d_in[8];
    const float* bk1  = (const float*)d_in[9];
    const float* Wk2  = (const float*)d_in[10];
    const float* bk2  = (const float*)d_in[11];
    const float* spdb = (const float*)d_in[12];
    const float* dse  = (const float*)d_in[13];
    const float* dde  = (const float*)d_in[14];
    const float* Wout = (const float*)d_in[15];
    const float* bout = (const float*)d_in[16];
    const float* bndr = (const float*)d_in[17];
    const int*   ei   = (const int*)d_in[18];
    const int*   deg  = (const int*)d_in[19];

    float* out   = (float*)d_out;
    float* outH  = out;
    float* outLq = out + (size_t)NN * HID;
    float* outLk = outLq + (size_t)NN * NB;

    // workspace: ~1.78 MB total
    int* wsp = (int*)d_ws;
    size_t o = 0;
    auto carve = [&](size_t n_ints) -> int* {
        int* p = wsp + o; o += n_ints; return p;
    };
    int* bcnt  = carve(NB);
    int* boff  = carve(NB + 1);
    int* bfill = carve(NB);
    int* blist = carve(NN);
    int* bqv   = carve(NN);
    int* bkv   = carve(NN);
    int* ecnt  = carve(NN);      // reused as kept-adjacency count after dedup
    int* eoff  = carve(NN + 1);
    int* efill = carve(NN);
    int* adj   = carve(NE);
    int* qoff  = carve(NB + 1);
    int* qlist = carve(NN);

    zero_kernel<<<(NB + 255) / 256, 256, 0, stream>>>(bcnt, NB);
    zero_kernel<<<(NN + 255) / 256, 256, 0, stream>>>(ecnt, NN);

    mlp_kernel<<<NN / 16, 256, 0, stream>>>(Q,  lap, Wq1, bq1, Wq2, bq2, outLq, bqv);
    mlp_kernel<<<NN / 16, 256, 0, stream>>>(Kx, lap, Wk1, bk1, Wk2, bk2, outLk, bkv);

    // K-side bucket lists (candidate sets)
    hist_kernel<<<(NN + 255) / 256, 256, 0, stream>>>(bkv, bcnt);
    scan_bucket_kernel<<<1, 1024, 0, stream>>>(bcnt, boff, bfill);
    scatter_bucket_kernel<<<(NN + 255) / 256, 256, 0, stream>>>(bkv, bfill, blist);

    // Q-side ordering: process nodes grouped by their query bucket (L2 locality)
    zero_kernel<<<(NB + 255) / 256, 256, 0, stream>>>(bcnt, NB);
    hist_kernel<<<(NN + 255) / 256, 256, 0, stream>>>(bqv, bcnt);
    scan_bucket_kernel<<<1, 1024, 0, stream>>>(bcnt, qoff, bfill);
    scatter_bucket_kernel<<<(NN + 255) / 256, 256, 0, stream>>>(bqv, bfill, qlist);

    // adjacency CSR
    edge_count_kernel<<<(NE + 255) / 256, 256, 0, stream>>>(ei, ecnt);
    scan_edge_kernel<<<1, 1024, 0, stream>>>(ecnt, eoff, efill);
    edge_scatter_kernel<<<(NE + 255) / 256, 256, 0, stream>>>(ei, efill, adj);

    // hoist dup/bucket filtering out of the hot loop
    dedup_kernel<<<NN / 4, 256, 0, stream>>>(eoff, adj, bqv, bkv, ecnt);

    attn_kernel<<<NN / 4, 256, 0, stream>>>(Q, Kx, Vx, lap, spdb, dse, dde, bndr, deg,
                                            bqv, boff, blist, eoff, ecnt, adj, qlist,
                                            Wout, bout, outH);
}

// Round 4
// 845.259 us; speedup vs baseline: 1.2100x; 1.0442x over previous
//
#include <hip/hip_runtime.h>
#include <math.h>

#define NN 20000
#define HID 128
#define NH 8
#define HD 16
#define LAPD 16
#define NB 1024
#define NBINS 32
#define MAXDEG 64
#define NE 320000
#define DIN 144

// finite "minus infinity" sentinel: never produces inf/NaN arithmetic,
// exp(x - NEGH) underflows to 0 in hardware. Real scores are |s| < ~1e4.
#define NEGH (-1.0e30f)

// ---------------- MLP: l = relu([X,lap]@W1+b1)@W2+b2, argmax over 1024 (fp32) ---
__global__ __launch_bounds__(256) void mlp_kernel(
    const float* __restrict__ X, const float* __restrict__ lap,
    const float* __restrict__ W1, const float* __restrict__ b1,
    const float* __restrict__ W2, const float* __restrict__ b2,
    float* __restrict__ outL, int* __restrict__ bidx)
{
    __shared__ __align__(16) float xs[16][DIN];
    __shared__ __align__(16) float hs[16][HID];
    __shared__ float rbv[64];
    __shared__ int   rbi[64];
    const int tid = threadIdx.x;
    const int n0 = blockIdx.x * 16;

    for (int e = tid; e < 16 * DIN; e += 256) {
        int n = e / DIN, k = e - n * DIN;
        float v = (k < HID) ? X[(size_t)(n0 + n) * HID + k]
                            : lap[(size_t)(n0 + n) * LAPD + (k - HID)];
        xs[n][k] = v;
    }
    __syncthreads();

    const int c = tid & 127, ng = tid >> 7;
    float hacc[8];
    {
        float bb = b1[c];
        #pragma unroll
        for (int m = 0; m < 8; m++) hacc[m] = bb;
        for (int k = 0; k < DIN; k += 4) {
            float w0 = W1[(k + 0) * HID + c];
            float w1 = W1[(k + 1) * HID + c];
            float w2 = W1[(k + 2) * HID + c];
            float w3 = W1[(k + 3) * HID + c];
            #pragma unroll
            for (int m = 0; m < 8; m++) {
                float4 xv = *(const float4*)&xs[ng * 8 + m][k];
                hacc[m] = fmaf(xv.x, w0, hacc[m]);
                hacc[m] = fmaf(xv.y, w1, hacc[m]);
                hacc[m] = fmaf(xv.z, w2, hacc[m]);
                hacc[m] = fmaf(xv.w, w3, hacc[m]);
            }
        }
    }
    #pragma unroll
    for (int m = 0; m < 8; m++) hs[ng * 8 + m][c] = fmaxf(hacc[m], 0.0f);
    __syncthreads();

    float a0[16], a1[16], a2[16], a3[16];
    #pragma unroll
    for (int m = 0; m < 16; m++) { a0[m] = 0.f; a1[m] = 0.f; a2[m] = 0.f; a3[m] = 0.f; }

    // software-pipelined W2 loads: next k-step's 4 float4s issue before the
    // 256-FMA body of the current step (hides ~200cy L2 latency under ~512cy VALU)
    const float* W2b = W2 + 4 * tid;
    float4 w0 = *(const float4*)&W2b[(size_t)0 * NB];
    float4 w1 = *(const float4*)&W2b[(size_t)1 * NB];
    float4 w2 = *(const float4*)&W2b[(size_t)2 * NB];
    float4 w3 = *(const float4*)&W2b[(size_t)3 * NB];
    for (int k = 0; k < HID; k += 4) {
        const int kn = (k + 4 < HID) ? (k + 4) : 0;   // clamp: harmless hot reload
        float4 nw0 = *(const float4*)&W2b[(size_t)(kn + 0) * NB];
        float4 nw1 = *(const float4*)&W2b[(size_t)(kn + 1) * NB];
        float4 nw2 = *(const float4*)&W2b[(size_t)(kn + 2) * NB];
        float4 nw3 = *(const float4*)&W2b[(size_t)(kn + 3) * NB];
        #pragma unroll
        for (int m = 0; m < 16; m++) {
            const float4 hv = *(const float4*)&hs[m][k];
            a0[m] = fmaf(hv.x, w0.x, fmaf(hv.y, w1.x, fmaf(hv.z, w2.x, fmaf(hv.w, w3.x, a0[m]))));
            a1[m] = fmaf(hv.x, w0.y, fmaf(hv.y, w1.y, fmaf(hv.z, w2.y, fmaf(hv.w, w3.y, a1[m]))));
            a2[m] = fmaf(hv.x, w0.z, fmaf(hv.y, w1.z, fmaf(hv.z, w2.z, fmaf(hv.w, w3.z, a2[m]))));
            a3[m] = fmaf(hv.x, w0.w, fmaf(hv.y, w1.w, fmaf(hv.z, w2.w, fmaf(hv.w, w3.w, a3[m]))));
        }
        w0 = nw0; w1 = nw1; w2 = nw2; w3 = nw3;
    }

    const float4 bb4 = *(const float4*)&b2[4 * tid];
    const int lane = tid & 63, wv = tid >> 6;
    const int o0 = 4 * tid;
    for (int m = 0; m < 16; m++) {
        float4 ov;
        ov.x = a0[m] + bb4.x; ov.y = a1[m] + bb4.y;
        ov.z = a2[m] + bb4.z; ov.w = a3[m] + bb4.w;
        *(float4*)&outL[(size_t)(n0 + m) * NB + o0] = ov;
        float bv = ov.x; int bi = o0;
        if (ov.y > bv) { bv = ov.y; bi = o0 + 1; }
        if (ov.z > bv) { bv = ov.z; bi = o0 + 2; }
        if (ov.w > bv) { bv = ov.w; bi = o0 + 3; }
        #pragma unroll
        for (int off = 1; off < 64; off <<= 1) {
            float ovv = __shfl_xor(bv, off, 64);
            int   oi  = __shfl_xor(bi, off, 64);
            if (ovv > bv || (ovv == bv && oi < bi)) { bv = ovv; bi = oi; }
        }
        if (lane == 0) { rbv[wv * 16 + m] = bv; rbi[wv * 16 + m] = bi; }
    }
    __syncthreads();
    if (tid < 16) {
        float bv = rbv[tid]; int bi = rbi[tid];
        #pragma unroll
        for (int ww = 1; ww < 4; ww++) {
            float ov = rbv[ww * 16 + tid]; int oi = rbi[ww * 16 + tid];
            if (ov > bv || (ov == bv && oi < bi)) { bv = ov; bi = oi; }
        }
        bidx[n0 + tid] = min(max(bi, 0), NB - 1);
    }
}

// ---------------- small utility kernels ----------------------------------------
__global__ void zero_kernel(int* __restrict__ p, int n) {
    int i = blockIdx.x * 256 + threadIdx.x;
    if (i < n) p[i] = 0;
}

__global__ void hist_kernel(const int* __restrict__ bkarr, int* __restrict__ bcnt) {
    int i = blockIdx.x * 256 + threadIdx.x;
    if (i < NN) {
        int b = min(max(bkarr[i], 0), NB - 1);
        atomicAdd(&bcnt[b], 1);
    }
}

__global__ __launch_bounds__(1024) void scan_bucket_kernel(const int* __restrict__ cnt,
        int* __restrict__ off, int* __restrict__ fill) {
    __shared__ int s[1024];
    int t = threadIdx.x;
    int v = cnt[t];
    s[t] = v; __syncthreads();
    for (int o = 1; o < 1024; o <<= 1) {
        int a = (t >= o) ? s[t - o] : 0;
        __syncthreads();
        s[t] += a;
        __syncthreads();
    }
    int excl = s[t] - v;
    off[t] = excl; fill[t] = excl;
    if (t == 1023) off[NB] = s[1023];
}

__global__ __launch_bounds__(1024) void scan_edge_kernel(const int* __restrict__ cnt,
        int* __restrict__ off, int* __restrict__ fill) {
    __shared__ int s[1024];
    const int t = threadIdx.x;
    const int base = t * 20;   // 1024*20 >= 20000
    int loc[20]; int sum = 0;
    #pragma unroll
    for (int k = 0; k < 20; k++) {
        int idx = base + k;
        int v = (idx < NN) ? cnt[idx] : 0;
        loc[k] = sum; sum += v;
    }
    s[t] = sum; __syncthreads();
    for (int o = 1; o < 1024; o <<= 1) {
        int a = (t >= o) ? s[t - o] : 0;
        __syncthreads();
        s[t] += a;
        __syncthreads();
    }
    int pre = s[t] - sum;
    #pragma unroll
    for (int k = 0; k < 20; k++) {
        int idx = base + k;
        if (idx < NN) { int e = pre + loc[k]; off[idx] = e; fill[idx] = e; }
    }
    if (t == 1023) off[NN] = s[1023];
}

__global__ void scatter_bucket_kernel(const int* __restrict__ bkarr,
        int* __restrict__ fill, int* __restrict__ blist) {
    int i = blockIdx.x * 256 + threadIdx.x;
    if (i < NN) {
        int b = min(max(bkarr[i], 0), NB - 1);
        int p = atomicAdd(&fill[b], 1);
        if (p >= 0 && p < NN) blist[p] = i;
    }
}

__global__ void edge_count_kernel(const int* __restrict__ ei, int* __restrict__ ecnt) {
    int e = blockIdx.x * 256 + threadIdx.x;
    if (e < NE) {
        int s = min(max(ei[e], 0), NN - 1);
        atomicAdd(&ecnt[s], 1);
    }
}

__global__ void edge_scatter_kernel(const int* __restrict__ ei,
        int* __restrict__ fill, int* __restrict__ adj) {
    int e = blockIdx.x * 256 + threadIdx.x;
    if (e < NE) {
        int s = min(max(ei[e], 0), NN - 1);
        int d = min(max(ei[NE + e], 0), NN - 1);
        int p = atomicAdd(&fill[s], 1);
        if (p >= 0 && p < NE) adj[p] = d;
    }
}

// ------- adjacency clean-up (off the hot path): per node, drop edges that are
// already covered by the LSH bucket ((j!=i && bk[j]==bq[i])) and duplicate
// edges (keep first occurrence). Compacts adj in place, writes kept count.
__global__ __launch_bounds__(256) void dedup_kernel(
    const int* __restrict__ eoff, int* __restrict__ adj,
    const int* __restrict__ bqv, const int* __restrict__ bkv,
    int* __restrict__ acnt)
{
    __shared__ int prev[4][192];
    const int lane = threadIdx.x & 63, wv = threadIdx.x >> 6;
    const int i = blockIdx.x * 4 + wv;
    if (i >= NN) return;
    int es = eoff[i], ee = eoff[i + 1];
    es = min(max(es, 0), NE); ee = min(max(ee, es), NE);
    const int d = ee - es;
    const int b = min(max(bqv[i], 0), NB - 1);
    int kept = 0;
    for (int t0 = 0; t0 < d; t0 += 64) {
        const int t = t0 + lane;
        const bool in = t < d;
        int j = -1;
        if (in) j = min(max(adj[es + t], 0), NN - 1);
        bool keep = in && ((j == i) || (bkv[j] != b));
        const int nin = min(64, d - t0);
        for (int q2 = 0; q2 < nin; q2++) {
            int jq = __shfl(j, q2, 64);
            if (in && q2 < lane && jq == j) keep = false;
        }
        if (t0 > 0 && in) {
            asm volatile("s_waitcnt lgkmcnt(0)" ::: "memory");
            const int np = min(t0, 192);
            for (int q2 = 0; q2 < np; q2++)
                if (prev[wv][q2] == j) keep = false;
        }
        if (in && t < 192) prev[wv][t] = j;   // record ORIGINAL value before compaction
        unsigned long long km = __ballot(keep);
        int pos = __popcll(km & ((1ull << lane) - 1ull));
        if (keep) adj[es + kept + pos] = j;   // write idx <= read idx: in-place safe
        kept += (int)__popcll(km);
    }
    if (lane == 0) acnt[i] = kept;
}

// ------- attention: 4 waves/block, 1 node/wave, bucket-ordered via qlist -------
// Phase A (candidate-major, lane=candidate): K gather + 8-head dots + biases.
// Softmax: per-head wave max; weights -> LDS transpose (same wave, no barrier).
// Phase B (quad-split PV): lane (c=lane>>2, q=lane&3) owns dims q*32..q*32+31.
// Writes NORMALIZED h to outH; out_gemm applies W_out afterward (in-place).
// No launch_bounds min: let the allocator keep the full ~110-reg live set in
// VGPRs (round-2's __launch_bounds__(256,3) caused scratch spills: WRITE_SIZE
// 170MB vs 10MB program writes).
__global__ __launch_bounds__(256) void attn_kernel(
    const float* __restrict__ Q, const float* __restrict__ K, const float* __restrict__ V,
    const float* __restrict__ lap,
    const float* __restrict__ spdb, const float* __restrict__ dse,
    const float* __restrict__ dde, const float* __restrict__ bndr,
    const int* __restrict__ deg,
    const int* __restrict__ bq,
    const int* __restrict__ boff, const int* __restrict__ blist,
    const int* __restrict__ eoff, const int* __restrict__ acnt,
    const int* __restrict__ adj, const int* __restrict__ qlist,
    float* __restrict__ outH)
{
    __shared__ __align__(16) float qfl[4][128];
    __shared__ __align__(16) float pefl[4][16];
    __shared__ float wts[4][8][66];
    __shared__ int   jls[4][64];
    __shared__ __align__(16) float spdbs[(NBINS + 1) * NH];   // 264
    __shared__ __align__(16) float ddes[(MAXDEG + 2) * NH];   // 528
    __shared__ float bnd[32];

    const int tid = threadIdx.x;
    const int wv = tid >> 6, lane = tid & 63;
    const int cq = lane >> 2, qq = lane & 3;   // candidate slot / dim-quarter

    // bijective XCD chunking: 5000 blocks = 8 * 625
    int blk = (int)blockIdx.x;
    blk = (blk & 7) * 625 + (blk >> 3);
    const int task = blk * 4 + wv;
    int i = qlist[task];
    i = min(max(i, 0), NN - 1);

    for (int e = tid; e < (NBINS + 1) * NH; e += 256) spdbs[e] = spdb[e];
    for (int e = tid; e < (MAXDEG + 2) * NH; e += 256) ddes[e] = dde[e];
    if (tid < 32) bnd[tid] = bndr[tid];
    qfl[wv][lane]      = Q[(size_t)i * HID + lane];
    qfl[wv][lane + 64] = Q[(size_t)i * HID + 64 + lane];
    if (lane < 16) pefl[wv][lane] = lap[(size_t)i * LAPD + lane];

    int b = min(max(bq[i], 0), NB - 1);
    int bs = boff[b], be = boff[b + 1];
    bs = min(max(bs, 0), NN); be = min(max(be, bs), NN);
    int es = eoff[i];
    es = min(max(es, 0), NE);
    int na = min(max(acnt[i], 0), NE - es);
    const int Lb = be - bs;
    const int Ltot = Lb + na;
    const int degi = min(max(deg[i], 0), MAXDEG + 1);

    // prefetch chunk 0's candidate index (overlaps the staging barrier)
    int jn = i; bool vn = false;
    if (lane < Ltot) {
        if (lane < Lb) {
            jn = min(max(blist[bs + lane], 0), NN - 1);
            vn = (jn != i);
        } else {
            jn = min(max(adj[es + (lane - Lb)], 0), NN - 1);
            vn = true;   // pre-deduped, pre-filtered
        }
    }
    __syncthreads();   // tables + per-wave staging visible

    const float4 ds0 = *(const float4*)&dse[degi * 8];
    const float4 ds1 = *(const float4*)&dse[degi * 8 + 4];

    float m8[8], l8[8];
    #pragma unroll
    for (int h = 0; h < 8; h++) { m8[h] = NEGH; l8[h] = 0.0f; }
    float acc[32];
    #pragma unroll
    for (int k = 0; k < 32; k++) acc[k] = 0.0f;

    for (int t0 = 0; t0 < Ltot; t0 += 64) {
        const int j = jn; const bool valid = vn;

        // ---- phase A: candidate-major scores ----
        float s8[8];
        if (valid) {
            const float4* K4 = (const float4*)(K + (size_t)j * HID);
            const float4* Q4 = (const float4*)&qfl[wv][0];
            #pragma unroll
            for (int h = 0; h < 8; h++) {
                float4 k0 = K4[h * 4 + 0], k1 = K4[h * 4 + 1];
                float4 k2 = K4[h * 4 + 2], k3 = K4[h * 4 + 3];
                float4 q0 = Q4[h * 4 + 0], q1 = Q4[h * 4 + 1];
                float4 q2 = Q4[h * 4 + 2], q3 = Q4[h * 4 + 3];
                float dot = 0.0f;
                dot = fmaf(q0.x, k0.x, dot); dot = fmaf(q0.y, k0.y, dot);
                dot = fmaf(q0.z, k0.z, dot); dot = fmaf(q0.w, k0.w, dot);
                dot = fmaf(q1.x, k1.x, dot); dot = fmaf(q1.y, k1.y, dot);
                dot = fmaf(q1.z, k1.z, dot); dot = fmaf(q1.w, k1.w, dot);
                dot = fmaf(q2.x, k2.x, dot); dot = fmaf(q2.y, k2.y, dot);
                dot = fmaf(q2.z, k2.z, dot); dot = fmaf(q2.w, k2.w, dot);
                dot = fmaf(q3.x, k3.x, dot); dot = fmaf(q3.y, k3.y, dot);
                dot = fmaf(q3.z, k3.z, dot); dot = fmaf(q3.w, k3.w, dot);
                s8[h] = dot * 0.25f;   // /sqrt(16)
            }
            const float4* P4 = (const float4*)&pefl[wv][0];
            const float4* L4 = (const float4*)(lap + (size_t)j * LAPD);
            float ss = 0.0f;
            #pragma unroll
            for (int d4 = 0; d4 < 4; d4++) {
                float4 pe = P4[d4], lj = L4[d4];
                float dx = pe.x - lj.x, dy = pe.y - lj.y;
                float dz = pe.z - lj.z, dw = pe.w - lj.w;
                ss = fmaf(dx, dx, ss); ss = fmaf(dy, dy, ss);
                ss = fmaf(dz, dz, ss); ss = fmaf(dw, dw, ss);
            }
            float dist = sqrtf(ss);
            int si = 0;
            #pragma unroll
            for (int kb = 0; kb < 32; kb++) si += (bnd[kb] < dist) ? 1 : 0;  // searchsorted left
            const int dj = min(max(deg[j], 0), MAXDEG + 1);
            const float4 sb0 = *(const float4*)&spdbs[si * 8];
            const float4 sb1 = *(const float4*)&spdbs[si * 8 + 4];
            const float4 db0 = *(const float4*)&ddes[dj * 8];
            const float4 db1 = *(const float4*)&ddes[dj * 8 + 4];
            s8[0] += sb0.x + ds0.x + db0.x; s8[1] += sb0.y + ds0.y + db0.y;
            s8[2] += sb0.z + ds0.z + db0.z; s8[3] += sb0.w + ds0.w + db0.w;
            s8[4] += sb1.x + ds1.x + db1.x; s8[5] += sb1.y + ds1.y + db1.y;
            s8[6] += sb1.z + ds1.z + db1.z; s8[7] += sb1.w + ds1.w + db1.w;
        } else {
            #pragma unroll
            for (int h = 0; h < 8; h++) s8[h] = NEGH;
        }
        jls[wv][lane] = valid ? j : i;

        // prefetch next chunk's candidate index (latency hidden under phase B)
        jn = i; vn = false;
        {
            const int t2 = t0 + 64 + lane;
            if (t2 < Ltot) {
                if (t2 < Lb) {
                    jn = min(max(blist[bs + t2], 0), NN - 1);
                    vn = (jn != i);
                } else {
                    jn = min(max(adj[es + (t2 - Lb)], 0), NN - 1);
                    vn = true;
                }
            }
        }

        // ---- softmax bookkeeping (m wave-uniform, l per-lane partial) ----
        float alpha8[8];
        #pragma unroll
        for (int h = 0; h < 8; h++) {
            float cm = s8[h];
            #pragma unroll
            for (int off = 1; off < 64; off <<= 1)
                cm = fmaxf(cm, __shfl_xor(cm, off, 64));
            const float mn = fmaxf(m8[h], cm);
            alpha8[h] = __expf(m8[h] - mn);
            const float p = valid ? __expf(s8[h] - mn) : 0.0f;
            l8[h] = l8[h] * alpha8[h] + p;
            m8[h] = mn;
            wts[wv][h][lane] = p;
        }

        // alpha for this lane's two heads (compile-time indices per arm)
        float aq0, aq1;
        if (qq == 0)      { aq0 = alpha8[0]; aq1 = alpha8[1]; }
        else if (qq == 1) { aq0 = alpha8[2]; aq1 = alpha8[3]; }
        else if (qq == 2) { aq0 = alpha8[4]; aq1 = alpha8[5]; }
        else              { aq0 = alpha8[6]; aq1 = alpha8[7]; }

        #pragma unroll
        for (int k = 0; k < 16; k++) acc[k] *= aq0;
        #pragma unroll
        for (int k = 16; k < 32; k++) acc[k] *= aq1;

        // same-wave LDS handoff: drain DS writes before cross-lane reads
        asm volatile("s_waitcnt lgkmcnt(0)" ::: "memory");

        // ---- phase B: quad-split PV ----
        const int rem = Ltot - t0;
        const int npass = ((rem < 64 ? rem : 64) + 15) >> 4;
        for (int r = 0; r < npass; r++) {
            const int cc = r * 16 + cq;
            const int jc = jls[wv][cc];
            const float w0 = wts[wv][2 * qq][cc];
            const float w1 = wts[wv][2 * qq + 1][cc];
            const float4* V4 = (const float4*)(V + (size_t)jc * HID + qq * 32);
            #pragma unroll
            for (int s = 0; s < 4; s++) {
                const float4 v = V4[s];
                acc[s * 4 + 0] = fmaf(w0, v.x, acc[s * 4 + 0]);
                acc[s * 4 + 1] = fmaf(w0, v.y, acc[s * 4 + 1]);
                acc[s * 4 + 2] = fmaf(w0, v.z, acc[s * 4 + 2]);
                acc[s * 4 + 3] = fmaf(w0, v.w, acc[s * 4 + 3]);
            }
            #pragma unroll
            for (int s = 4; s < 8; s++) {
                const float4 v = V4[s];
                acc[s * 4 + 0] = fmaf(w1, v.x, acc[s * 4 + 0]);
                acc[s * 4 + 1] = fmaf(w1, v.y, acc[s * 4 + 1]);
                acc[s * 4 + 2] = fmaf(w1, v.z, acc[s * 4 + 2]);
                acc[s * 4 + 3] = fmaf(w1, v.w, acc[s * 4 + 3]);
            }
        }
    }

    // ---- final reduces ----
    #pragma unroll
    for (int h = 0; h < 8; h++) {
        float v = l8[h];
        #pragma unroll
        for (int off = 1; off < 64; off <<= 1) v += __shfl_xor(v, off, 64);
        l8[h] = v;
    }
    float lq0, lq1;
    if (qq == 0)      { lq0 = l8[0]; lq1 = l8[1]; }
    else if (qq == 1) { lq0 = l8[2]; lq1 = l8[3]; }
    else if (qq == 2) { lq0 = l8[4]; lq1 = l8[5]; }
    else              { lq0 = l8[6]; lq1 = l8[7]; }
    const float linv0 = 1.0f / (lq0 + 1e-16f);
    const float linv1 = 1.0f / (lq1 + 1e-16f);
    #pragma unroll
    for (int k = 0; k < 16; k++) acc[k] *= linv0;
    #pragma unroll
    for (int k = 16; k < 32; k++) acc[k] *= linv1;

    // butterfly-sum over the 16 candidate-slot lanes (xor bits 2..5)
    #pragma unroll
    for (int k = 0; k < 32; k++) {
        float v = acc[k];
        v += __shfl_xor(v, 4, 64);
        v += __shfl_xor(v, 8, 64);
        v += __shfl_xor(v, 16, 64);
        v += __shfl_xor(v, 32, 64);
        acc[k] = v;
    }
    if (cq == 0) {   // lanes 0..3; lane qq writes dims qq*32..qq*32+31 (h, pre-W_out)
        float4* orow = (float4*)(outH + (size_t)i * HID + qq * 32);
        #pragma unroll
        for (int s = 0; s < 8; s++)
            orow[s] = make_float4(acc[s * 4 + 0], acc[s * 4 + 1],
                                  acc[s * 4 + 2], acc[s * 4 + 3]);
    }
}

// ------- out = h @ W_out + b_out, in-place on outH (each block owns its rows) --
__global__ __launch_bounds__(256) void out_gemm_kernel(
    const float* __restrict__ Wout, const float* __restrict__ bout,
    float* __restrict__ outH)
{
    __shared__ __align__(16) float hsT[32][HID];   // 16 KB
    const int tid = threadIdx.x;
    const int r0 = blockIdx.x * 32;

    // stage this block's 32x128 h tile (coalesced float4), then it's safe to
    // overwrite those same rows
    for (int e = tid; e < 32 * 32; e += 256) {
        const int r = e >> 5, c4 = e & 31;
        ((float4*)&hsT[r][0])[c4] = ((const float4*)&outH[(size_t)(r0 + r) * HID])[c4];
    }
    __syncthreads();

    const int c = tid & 127;     // output column
    const int mg = tid >> 7;     // row group: rows mg*16 .. mg*16+15
    float acc[16];
    const float bb = bout[c];
    #pragma unroll
    for (int m = 0; m < 16; m++) acc[m] = bb;

    for (int k = 0; k < HID; k += 4) {
        const float w0 = Wout[(size_t)(k + 0) * HID + c];
        const float w1 = Wout[(size_t)(k + 1) * HID + c];
        const float w2 = Wout[(size_t)(k + 2) * HID + c];
        const float w3 = Wout[(size_t)(k + 3) * HID + c];
        #pragma unroll
        for (int m = 0; m < 16; m++) {
            const float4 hv = *(const float4*)&hsT[mg * 16 + m][k];
            acc[m] = fmaf(hv.x, w0, fmaf(hv.y, w1, fmaf(hv.z, w2, fmaf(hv.w, w3, acc[m]))));
        }
    }
    #pragma unroll
    for (int m = 0; m < 16; m++)
        outH[(size_t)(r0 + mg * 16 + m) * HID + c] = acc[m];
}

// ---------------- launch --------------------------------------------------------
extern "C" void kernel_launch(void* const* d_in, const int* in_sizes, int n_in,
                              void* d_out, int out_size, void* d_ws, size_t ws_size,
                              hipStream_t stream) {
    const float* Q    = (const float*)d_in[0];
    const float* Kx   = (const float*)d_in[1];
    const float* Vx   = (const float*)d_in[2];
    const float* lap  = (const float*)d_in[3];
    const float* Wq1  = (const float*)d_in[4];
    const float* bq1  = (const float*)d_in[5];
    const float* Wq2  = (const float*)d_in[6];
    const float* bq2  = (const float*)d_in[7];
    const float* Wk1  = (const float*)d_in[8];
    const float* bk1  = (const float*)d_in[9];
    const float* Wk2  = (const float*)d_in[10];
    const float* bk2  = (const float*)d_in[11];
    const float* spdb = (const float*)d_in[12];
    const float* dse  = (const float*)d_in[13];
    const float* dde  = (const float*)d_in[14];
    const float* Wout = (const float*)d_in[15];
    const float* bout = (const float*)d_in[16];
    const float* bndr = (const float*)d_in[17];
    const int*   ei   = (const int*)d_in[18];
    const int*   deg  = (const int*)d_in[19];

    float* out   = (float*)d_out;
    float* outH  = out;
    float* outLq = out + (size_t)NN * HID;
    float* outLk = outLq + (size_t)NN * NB;

    // workspace: ~1.86 MB total
    int* wsp = (int*)d_ws;
    size_t o = 0;
    auto carve = [&](size_t n_ints) -> int* {
        int* p = wsp + o; o += n_ints; return p;
    };
    int* bcnt  = carve(NB);
    int* boff  = carve(NB + 1);
    int* bfill = carve(NB);
    int* blist = carve(NN);
    int* bqv   = carve(NN);
    int* bkv   = carve(NN);
    int* ecnt  = carve(NN);      // reused as kept-adjacency count after dedup
    int* eoff  = carve(NN + 1);
    int* efill = carve(NN);
    int* adj   = carve(NE);
    int* qoff  = carve(NB + 1);
    int* qlist = carve(NN);

    zero_kernel<<<(NB + 255) / 256, 256, 0, stream>>>(bcnt, NB);
    zero_kernel<<<(NN + 255) / 256, 256, 0, stream>>>(ecnt, NN);

    mlp_kernel<<<NN / 16, 256, 0, stream>>>(Q,  lap, Wq1, bq1, Wq2, bq2, outLq, bqv);
    mlp_kernel<<<NN / 16, 256, 0, stream>>>(Kx, lap, Wk1, bk1, Wk2, bk2, outLk, bkv);

    // K-side bucket lists (candidate sets)
    hist_kernel<<<(NN + 255) / 256, 256, 0, stream>>>(bkv, bcnt);
    scan_bucket_kernel<<<1, 1024, 0, stream>>>(bcnt, boff, bfill);
    scatter_bucket_kernel<<<(NN + 255) / 256, 256, 0, stream>>>(bkv, bfill, blist);

    // Q-side ordering: process nodes grouped by their query bucket (L2 locality)
    zero_kernel<<<(NB + 255) / 256, 256, 0, stream>>>(bcnt, NB);
    hist_kernel<<<(NN + 255) / 256, 256, 0, stream>>>(bqv, bcnt);
    scan_bucket_kernel<<<1, 1024, 0, stream>>>(bcnt, qoff, bfill);
    scatter_bucket_kernel<<<(NN + 255) / 256, 256, 0, stream>>>(bqv, bfill, qlist);

    // adjacency CSR
    edge_count_kernel<<<(NE + 255) / 256, 256, 0, stream>>>(ei, ecnt);
    scan_edge_kernel<<<1, 1024, 0, stream>>>(ecnt, eoff, efill);
    edge_scatter_kernel<<<(NE + 255) / 256, 256, 0, stream>>>(ei, efill, adj);

    // hoist dup/bucket filtering out of the hot loop
    dedup_kernel<<<NN / 4, 256, 0, stream>>>(eoff, adj, bqv, bkv, ecnt);

    attn_kernel<<<NN / 4, 256, 0, stream>>>(Q, Kx, Vx, lap, spdb, dse, dde, bndr, deg,
                                            bqv, boff, blist, eoff, ecnt, adj, qlist,
                                            outH);

    out_gemm_kernel<<<NN / 32, 256, 0, stream>>>(Wout, bout, outH);
}

// Round 5
// 832.240 us; speedup vs baseline: 1.2290x; 1.0156x over previous
//
#include <hip/hip_runtime.h>
#include <math.h>

#define NN 20000
#define HID 128
#define NH 8
#define HD 16
#define LAPD 16
#define NB 1024
#define NBINS 32
#define MAXDEG 64
#define NE 320000
#define DIN 144

// finite "minus infinity" sentinel: never produces inf/NaN arithmetic,
// exp(x - NEGH) underflows to 0 in hardware. Real scores are |s| < ~1e4.
#define NEGH (-1.0e30f)

// ---------------- MLP: l = relu([X,lap]@W1+b1)@W2+b2, argmax over 1024 (fp32) ---
__global__ __launch_bounds__(256) void mlp_kernel(
    const float* __restrict__ X, const float* __restrict__ lap,
    const float* __restrict__ W1, const float* __restrict__ b1,
    const float* __restrict__ W2, const float* __restrict__ b2,
    float* __restrict__ outL, int* __restrict__ bidx)
{
    __shared__ __align__(16) float xs[16][DIN];
    __shared__ __align__(16) float hs[16][HID];
    __shared__ float rbv[64];
    __shared__ int   rbi[64];
    const int tid = threadIdx.x;
    const int n0 = blockIdx.x * 16;

    for (int e = tid; e < 16 * DIN; e += 256) {
        int n = e / DIN, k = e - n * DIN;
        float v = (k < HID) ? X[(size_t)(n0 + n) * HID + k]
                            : lap[(size_t)(n0 + n) * LAPD + (k - HID)];
        xs[n][k] = v;
    }
    __syncthreads();

    const int c = tid & 127, ng = tid >> 7;
    float hacc[8];
    {
        float bb = b1[c];
        #pragma unroll
        for (int m = 0; m < 8; m++) hacc[m] = bb;
        for (int k = 0; k < DIN; k += 4) {
            float w0 = W1[(k + 0) * HID + c];
            float w1 = W1[(k + 1) * HID + c];
            float w2 = W1[(k + 2) * HID + c];
            float w3 = W1[(k + 3) * HID + c];
            #pragma unroll
            for (int m = 0; m < 8; m++) {
                float4 xv = *(const float4*)&xs[ng * 8 + m][k];
                hacc[m] = fmaf(xv.x, w0, hacc[m]);
                hacc[m] = fmaf(xv.y, w1, hacc[m]);
                hacc[m] = fmaf(xv.z, w2, hacc[m]);
                hacc[m] = fmaf(xv.w, w3, hacc[m]);
            }
        }
    }
    #pragma unroll
    for (int m = 0; m < 8; m++) hs[ng * 8 + m][c] = fmaxf(hacc[m], 0.0f);
    __syncthreads();

    float a0[16], a1[16], a2[16], a3[16];
    #pragma unroll
    for (int m = 0; m < 16; m++) { a0[m] = 0.f; a1[m] = 0.f; a2[m] = 0.f; a3[m] = 0.f; }

    // software-pipelined W2 loads: next k-step's 4 float4s issue before the
    // 256-FMA body of the current step (hides ~200cy L2 latency under ~512cy VALU)
    const float* W2b = W2 + 4 * tid;
    float4 w0 = *(const float4*)&W2b[(size_t)0 * NB];
    float4 w1 = *(const float4*)&W2b[(size_t)1 * NB];
    float4 w2 = *(const float4*)&W2b[(size_t)2 * NB];
    float4 w3 = *(const float4*)&W2b[(size_t)3 * NB];
    for (int k = 0; k < HID; k += 4) {
        const int kn = (k + 4 < HID) ? (k + 4) : 0;   // clamp: harmless hot reload
        float4 nw0 = *(const float4*)&W2b[(size_t)(kn + 0) * NB];
        float4 nw1 = *(const float4*)&W2b[(size_t)(kn + 1) * NB];
        float4 nw2 = *(const float4*)&W2b[(size_t)(kn + 2) * NB];
        float4 nw3 = *(const float4*)&W2b[(size_t)(kn + 3) * NB];
        #pragma unroll
        for (int m = 0; m < 16; m++) {
            const float4 hv = *(const float4*)&hs[m][k];
            a0[m] = fmaf(hv.x, w0.x, fmaf(hv.y, w1.x, fmaf(hv.z, w2.x, fmaf(hv.w, w3.x, a0[m]))));
            a1[m] = fmaf(hv.x, w0.y, fmaf(hv.y, w1.y, fmaf(hv.z, w2.y, fmaf(hv.w, w3.y, a1[m]))));
            a2[m] = fmaf(hv.x, w0.z, fmaf(hv.y, w1.z, fmaf(hv.z, w2.z, fmaf(hv.w, w3.z, a2[m]))));
            a3[m] = fmaf(hv.x, w0.w, fmaf(hv.y, w1.w, fmaf(hv.z, w2.w, fmaf(hv.w, w3.w, a3[m]))));
        }
        w0 = nw0; w1 = nw1; w2 = nw2; w3 = nw3;
    }

    const float4 bb4 = *(const float4*)&b2[4 * tid];
    const int lane = tid & 63, wv = tid >> 6;
    const int o0 = 4 * tid;
    for (int m = 0; m < 16; m++) {
        float4 ov;
        ov.x = a0[m] + bb4.x; ov.y = a1[m] + bb4.y;
        ov.z = a2[m] + bb4.z; ov.w = a3[m] + bb4.w;
        *(float4*)&outL[(size_t)(n0 + m) * NB + o0] = ov;
        float bv = ov.x; int bi = o0;
        if (ov.y > bv) { bv = ov.y; bi = o0 + 1; }
        if (ov.z > bv) { bv = ov.z; bi = o0 + 2; }
        if (ov.w > bv) { bv = ov.w; bi = o0 + 3; }
        #pragma unroll
        for (int off = 1; off < 64; off <<= 1) {
            float ovv = __shfl_xor(bv, off, 64);
            int   oi  = __shfl_xor(bi, off, 64);
            if (ovv > bv || (ovv == bv && oi < bi)) { bv = ovv; bi = oi; }
        }
        if (lane == 0) { rbv[wv * 16 + m] = bv; rbi[wv * 16 + m] = bi; }
    }
    __syncthreads();
    if (tid < 16) {
        float bv = rbv[tid]; int bi = rbi[tid];
        #pragma unroll
        for (int ww = 1; ww < 4; ww++) {
            float ov = rbv[ww * 16 + tid]; int oi = rbi[ww * 16 + tid];
            if (ov > bv || (ov == bv && oi < bi)) { bv = ov; bi = oi; }
        }
        bidx[n0 + tid] = min(max(bi, 0), NB - 1);
    }
}

// ---------------- small utility kernels ----------------------------------------
__global__ void zero_kernel(int* __restrict__ p, int n) {
    int i = blockIdx.x * 256 + threadIdx.x;
    if (i < n) p[i] = 0;
}

__global__ void hist_kernel(const int* __restrict__ bkarr, int* __restrict__ bcnt) {
    int i = blockIdx.x * 256 + threadIdx.x;
    if (i < NN) {
        int b = min(max(bkarr[i], 0), NB - 1);
        atomicAdd(&bcnt[b], 1);
    }
}

__global__ __launch_bounds__(1024) void scan_bucket_kernel(const int* __restrict__ cnt,
        int* __restrict__ off, int* __restrict__ fill) {
    __shared__ int s[1024];
    int t = threadIdx.x;
    int v = cnt[t];
    s[t] = v; __syncthreads();
    for (int o = 1; o < 1024; o <<= 1) {
        int a = (t >= o) ? s[t - o] : 0;
        __syncthreads();
        s[t] += a;
        __syncthreads();
    }
    int excl = s[t] - v;
    off[t] = excl; fill[t] = excl;
    if (t == 1023) off[NB] = s[1023];
}

// ------- longest-job-first ordering: sort buckets by K-side size descending
// (bitonic, 1024 keys), then prefix-scan Q-side counts in that order and emit
// per-bucket scatter bases. Nodes of the biggest buckets (the stragglers)
// get the lowest qlist positions -> dispatched first -> no low-occupancy tail.
__global__ __launch_bounds__(1024) void order_kernel(
    const int* __restrict__ boff,    // K-side bucket offsets (kcnt = diff)
    const int* __restrict__ qcnt,    // Q-side bucket counts
    int* __restrict__ qfill)         // out: per-bucket scatter base
{
    __shared__ int kk[1024];
    __shared__ int ii[1024];
    __shared__ int ss[1024];
    const int t = threadIdx.x;
    kk[t] = boff[t + 1] - boff[t];
    ii[t] = t;
    __syncthreads();
    // bitonic sort, DESCENDING by key (any permutation is correct; this one
    // just sets the schedule)
    for (int size = 2; size <= 1024; size <<= 1) {
        for (int stride = size >> 1; stride > 0; stride >>= 1) {
            const int p = t ^ stride;
            if (p > t) {
                const int k1 = kk[t], k2 = kk[p];
                const bool up = ((t & size) == 0);
                if ((k1 < k2) == up) {
                    const int i1 = ii[t];
                    kk[t] = k2; kk[p] = k1;
                    ii[t] = ii[p]; ii[p] = i1;
                }
            }
            __syncthreads();
        }
    }
    const int v = qcnt[ii[t]];
    ss[t] = v; __syncthreads();
    for (int o = 1; o < 1024; o <<= 1) {
        int a = (t >= o) ? ss[t - o] : 0;
        __syncthreads();
        ss[t] += a;
        __syncthreads();
    }
    qfill[ii[t]] = ss[t] - v;
}

__global__ void scatter_bucket_kernel(const int* __restrict__ bkarr,
        int* __restrict__ fill, int* __restrict__ blist) {
    int i = blockIdx.x * 256 + threadIdx.x;
    if (i < NN) {
        int b = min(max(bkarr[i], 0), NB - 1);
        int p = atomicAdd(&fill[b], 1);
        if (p >= 0 && p < NN) blist[p] = i;
    }
}

__global__ __launch_bounds__(1024) void scan_edge_kernel(const int* __restrict__ cnt,
        int* __restrict__ off, int* __restrict__ fill) {
    __shared__ int s[1024];
    const int t = threadIdx.x;
    const int base = t * 20;   // 1024*20 >= 20000
    int loc[20]; int sum = 0;
    #pragma unroll
    for (int k = 0; k < 20; k++) {
        int idx = base + k;
        int v = (idx < NN) ? cnt[idx] : 0;
        loc[k] = sum; sum += v;
    }
    s[t] = sum; __syncthreads();
    for (int o = 1; o < 1024; o <<= 1) {
        int a = (t >= o) ? s[t - o] : 0;
        __syncthreads();
        s[t] += a;
        __syncthreads();
    }
    int pre = s[t] - sum;
    #pragma unroll
    for (int k = 0; k < 20; k++) {
        int idx = base + k;
        if (idx < NN) { int e = pre + loc[k]; off[idx] = e; fill[idx] = e; }
    }
    if (t == 1023) off[NN] = s[1023];
}

__global__ void edge_count_kernel(const int* __restrict__ ei, int* __restrict__ ecnt) {
    int e = blockIdx.x * 256 + threadIdx.x;
    if (e < NE) {
        int s = min(max(ei[e], 0), NN - 1);
        atomicAdd(&ecnt[s], 1);
    }
}

__global__ void edge_scatter_kernel(const int* __restrict__ ei,
        int* __restrict__ fill, int* __restrict__ adj) {
    int e = blockIdx.x * 256 + threadIdx.x;
    if (e < NE) {
        int s = min(max(ei[e], 0), NN - 1);
        int d = min(max(ei[NE + e], 0), NN - 1);
        int p = atomicAdd(&fill[s], 1);
        if (p >= 0 && p < NE) adj[p] = d;
    }
}

// ------- adjacency clean-up (off the hot path): per node, drop edges that are
// already covered by the LSH bucket ((j!=i && bk[j]==bq[i])) and duplicate
// edges (keep first occurrence). Compacts adj in place, writes kept count.
__global__ __launch_bounds__(256) void dedup_kernel(
    const int* __restrict__ eoff, int* __restrict__ adj,
    const int* __restrict__ bqv, const int* __restrict__ bkv,
    int* __restrict__ acnt)
{
    __shared__ int prev[4][192];
    const int lane = threadIdx.x & 63, wv = threadIdx.x >> 6;
    const int i = blockIdx.x * 4 + wv;
    if (i >= NN) return;
    int es = eoff[i], ee = eoff[i + 1];
    es = min(max(es, 0), NE); ee = min(max(ee, es), NE);
    const int d = ee - es;
    const int b = min(max(bqv[i], 0), NB - 1);
    int kept = 0;
    for (int t0 = 0; t0 < d; t0 += 64) {
        const int t = t0 + lane;
        const bool in = t < d;
        int j = -1;
        if (in) j = min(max(adj[es + t], 0), NN - 1);
        bool keep = in && ((j == i) || (bkv[j] != b));
        const int nin = min(64, d - t0);
        for (int q2 = 0; q2 < nin; q2++) {
            int jq = __shfl(j, q2, 64);
            if (in && q2 < lane && jq == j) keep = false;
        }
        if (t0 > 0 && in) {
            asm volatile("s_waitcnt lgkmcnt(0)" ::: "memory");
            const int np = min(t0, 192);
            for (int q2 = 0; q2 < np; q2++)
                if (prev[wv][q2] == j) keep = false;
        }
        if (in && t < 192) prev[wv][t] = j;   // record ORIGINAL value before compaction
        unsigned long long km = __ballot(keep);
        int pos = __popcll(km & ((1ull << lane) - 1ull));
        if (keep) adj[es + kept + pos] = j;   // write idx <= read idx: in-place safe
        kept += (int)__popcll(km);
    }
    if (lane == 0) acnt[i] = kept;
}

// ------- attention: 4 waves/block, 1 node/wave, big-bucket-first via qlist ----
// Phase A (candidate-major, lane=candidate): K gather + 8-head dots + biases.
// Softmax: per-head wave max; weights -> LDS transpose (same wave, no barrier).
// Phase B (quad-split PV): lane (c=lane>>2, q=lane&3) owns dims q*32..q*32+31.
// Writes NORMALIZED h to outH; out_gemm applies W_out afterward (in-place).
__global__ __launch_bounds__(256) void attn_kernel(
    const float* __restrict__ Q, const float* __restrict__ K, const float* __restrict__ V,
    const float* __restrict__ lap,
    const float* __restrict__ spdb, const float* __restrict__ dse,
    const float* __restrict__ dde, const float* __restrict__ bndr,
    const int* __restrict__ deg,
    const int* __restrict__ bq,
    const int* __restrict__ boff, const int* __restrict__ blist,
    const int* __restrict__ eoff, const int* __restrict__ acnt,
    const int* __restrict__ adj, const int* __restrict__ qlist,
    float* __restrict__ outH)
{
    __shared__ __align__(16) float qfl[4][128];
    __shared__ __align__(16) float pefl[4][16];
    __shared__ float wts[4][8][66];
    __shared__ int   jls[4][64];
    __shared__ __align__(16) float spdbs[(NBINS + 1) * NH];   // 264
    __shared__ __align__(16) float ddes[(MAXDEG + 2) * NH];   // 528
    __shared__ float bnd[32];

    const int tid = threadIdx.x;
    const int wv = tid >> 6, lane = tid & 63;
    const int cq = lane >> 2, qq = lane & 3;   // candidate slot / dim-quarter

    // NO XCD remap: qlist is longest-job-first; dispatch ~= blockIdx order,
    // so the straggler waves start at t=0 and backfill keeps occupancy high.
    const int task = (int)blockIdx.x * 4 + wv;
    int i = qlist[task];
    i = min(max(i, 0), NN - 1);

    for (int e = tid; e < (NBINS + 1) * NH; e += 256) spdbs[e] = spdb[e];
    for (int e = tid; e < (MAXDEG + 2) * NH; e += 256) ddes[e] = dde[e];
    if (tid < 32) bnd[tid] = bndr[tid];
    qfl[wv][lane]      = Q[(size_t)i * HID + lane];
    qfl[wv][lane + 64] = Q[(size_t)i * HID + 64 + lane];
    if (lane < 16) pefl[wv][lane] = lap[(size_t)i * LAPD + lane];

    int b = min(max(bq[i], 0), NB - 1);
    int bs = boff[b], be = boff[b + 1];
    bs = min(max(bs, 0), NN); be = min(max(be, bs), NN);
    int es = eoff[i];
    es = min(max(es, 0), NE);
    int na = min(max(acnt[i], 0), NE - es);
    const int Lb = be - bs;
    const int Ltot = Lb + na;
    const int degi = min(max(deg[i], 0), MAXDEG + 1);

    // prefetch chunk 0's candidate index (overlaps the staging barrier)
    int jn = i; bool vn = false;
    if (lane < Ltot) {
        if (lane < Lb) {
            jn = min(max(blist[bs + lane], 0), NN - 1);
            vn = (jn != i);
        } else {
            jn = min(max(adj[es + (lane - Lb)], 0), NN - 1);
            vn = true;   // pre-deduped, pre-filtered
        }
    }
    __syncthreads();   // tables + per-wave staging visible

    const float4 ds0 = *(const float4*)&dse[degi * 8];
    const float4 ds1 = *(const float4*)&dse[degi * 8 + 4];

    float m8[8], l8[8];
    #pragma unroll
    for (int h = 0; h < 8; h++) { m8[h] = NEGH; l8[h] = 0.0f; }
    float acc[32];
    #pragma unroll
    for (int k = 0; k < 32; k++) acc[k] = 0.0f;

    for (int t0 = 0; t0 < Ltot; t0 += 64) {
        const int j = jn; const bool valid = vn;

        // ---- phase A: candidate-major scores ----
        float s8[8];
        if (valid) {
            const float4* K4 = (const float4*)(K + (size_t)j * HID);
            const float4* Q4 = (const float4*)&qfl[wv][0];
            #pragma unroll
            for (int h = 0; h < 8; h++) {
                float4 k0 = K4[h * 4 + 0], k1 = K4[h * 4 + 1];
                float4 k2 = K4[h * 4 + 2], k3 = K4[h * 4 + 3];
                float4 q0 = Q4[h * 4 + 0], q1 = Q4[h * 4 + 1];
                float4 q2 = Q4[h * 4 + 2], q3 = Q4[h * 4 + 3];
                float dot = 0.0f;
                dot = fmaf(q0.x, k0.x, dot); dot = fmaf(q0.y, k0.y, dot);
                dot = fmaf(q0.z, k0.z, dot); dot = fmaf(q0.w, k0.w, dot);
                dot = fmaf(q1.x, k1.x, dot); dot = fmaf(q1.y, k1.y, dot);
                dot = fmaf(q1.z, k1.z, dot); dot = fmaf(q1.w, k1.w, dot);
                dot = fmaf(q2.x, k2.x, dot); dot = fmaf(q2.y, k2.y, dot);
                dot = fmaf(q2.z, k2.z, dot); dot = fmaf(q2.w, k2.w, dot);
                dot = fmaf(q3.x, k3.x, dot); dot = fmaf(q3.y, k3.y, dot);
                dot = fmaf(q3.z, k3.z, dot); dot = fmaf(q3.w, k3.w, dot);
                s8[h] = dot * 0.25f;   // /sqrt(16)
            }
            const float4* P4 = (const float4*)&pefl[wv][0];
            const float4* L4 = (const float4*)(lap + (size_t)j * LAPD);
            float ss = 0.0f;
            #pragma unroll
            for (int d4 = 0; d4 < 4; d4++) {
                float4 pe = P4[d4], lj = L4[d4];
                float dx = pe.x - lj.x, dy = pe.y - lj.y;
                float dz = pe.z - lj.z, dw = pe.w - lj.w;
                ss = fmaf(dx, dx, ss); ss = fmaf(dy, dy, ss);
                ss = fmaf(dz, dz, ss); ss = fmaf(dw, dw, ss);
            }
            float dist = sqrtf(ss);
            int si = 0;
            #pragma unroll
            for (int kb = 0; kb < 32; kb++) si += (bnd[kb] < dist) ? 1 : 0;  // searchsorted left
            const int dj = min(max(deg[j], 0), MAXDEG + 1);
            const float4 sb0 = *(const float4*)&spdbs[si * 8];
            const float4 sb1 = *(const float4*)&spdbs[si * 8 + 4];
            const float4 db0 = *(const float4*)&ddes[dj * 8];
            const float4 db1 = *(const float4*)&ddes[dj * 8 + 4];
            s8[0] += sb0.x + ds0.x + db0.x; s8[1] += sb0.y + ds0.y + db0.y;
            s8[2] += sb0.z + ds0.z + db0.z; s8[3] += sb0.w + ds0.w + db0.w;
            s8[4] += sb1.x + ds1.x + db1.x; s8[5] += sb1.y + ds1.y + db1.y;
            s8[6] += sb1.z + ds1.z + db1.z; s8[7] += sb1.w + ds1.w + db1.w;
        } else {
            #pragma unroll
            for (int h = 0; h < 8; h++) s8[h] = NEGH;
        }
        jls[wv][lane] = valid ? j : i;

        // prefetch next chunk's candidate index (latency hidden under phase B)
        jn = i; vn = false;
        {
            const int t2 = t0 + 64 + lane;
            if (t2 < Ltot) {
                if (t2 < Lb) {
                    jn = min(max(blist[bs + t2], 0), NN - 1);
                    vn = (jn != i);
                } else {
                    jn = min(max(adj[es + (t2 - Lb)], 0), NN - 1);
                    vn = true;
                }
            }
        }

        // ---- softmax bookkeeping (m wave-uniform, l per-lane partial) ----
        float alpha8[8];
        #pragma unroll
        for (int h = 0; h < 8; h++) {
            float cm = s8[h];
            #pragma unroll
            for (int off = 1; off < 64; off <<= 1)
                cm = fmaxf(cm, __shfl_xor(cm, off, 64));
            const float mn = fmaxf(m8[h], cm);
            alpha8[h] = __expf(m8[h] - mn);
            const float p = valid ? __expf(s8[h] - mn) : 0.0f;
            l8[h] = l8[h] * alpha8[h] + p;
            m8[h] = mn;
            wts[wv][h][lane] = p;
        }

        // alpha for this lane's two heads (compile-time indices per arm)
        float aq0, aq1;
        if (qq == 0)      { aq0 = alpha8[0]; aq1 = alpha8[1]; }
        else if (qq == 1) { aq0 = alpha8[2]; aq1 = alpha8[3]; }
        else if (qq == 2) { aq0 = alpha8[4]; aq1 = alpha8[5]; }
        else              { aq0 = alpha8[6]; aq1 = alpha8[7]; }

        #pragma unroll
        for (int k = 0; k < 16; k++) acc[k] *= aq0;
        #pragma unroll
        for (int k = 16; k < 32; k++) acc[k] *= aq1;

        // same-wave LDS handoff: drain DS writes before cross-lane reads
        asm volatile("s_waitcnt lgkmcnt(0)" ::: "memory");

        // ---- phase B: quad-split PV ----
        const int rem = Ltot - t0;
        const int npass = ((rem < 64 ? rem : 64) + 15) >> 4;
        for (int r = 0; r < npass; r++) {
            const int cc = r * 16 + cq;
            const int jc = jls[wv][cc];
            const float w0 = wts[wv][2 * qq][cc];
            const float w1 = wts[wv][2 * qq + 1][cc];
            const float4* V4 = (const float4*)(V + (size_t)jc * HID + qq * 32);
            #pragma unroll
            for (int s = 0; s < 4; s++) {
                const float4 v = V4[s];
                acc[s * 4 + 0] = fmaf(w0, v.x, acc[s * 4 + 0]);
                acc[s * 4 + 1] = fmaf(w0, v.y, acc[s * 4 + 1]);
                acc[s * 4 + 2] = fmaf(w0, v.z, acc[s * 4 + 2]);
                acc[s * 4 + 3] = fmaf(w0, v.w, acc[s * 4 + 3]);
            }
            #pragma unroll
            for (int s = 4; s < 8; s++) {
                const float4 v = V4[s];
                acc[s * 4 + 0] = fmaf(w1, v.x, acc[s * 4 + 0]);
                acc[s * 4 + 1] = fmaf(w1, v.y, acc[s * 4 + 1]);
                acc[s * 4 + 2] = fmaf(w1, v.z, acc[s * 4 + 2]);
                acc[s * 4 + 3] = fmaf(w1, v.w, acc[s * 4 + 3]);
            }
        }
    }

    // ---- final reduces ----
    #pragma unroll
    for (int h = 0; h < 8; h++) {
        float v = l8[h];
        #pragma unroll
        for (int off = 1; off < 64; off <<= 1) v += __shfl_xor(v, off, 64);
        l8[h] = v;
    }
    float lq0, lq1;
    if (qq == 0)      { lq0 = l8[0]; lq1 = l8[1]; }
    else if (qq == 1) { lq0 = l8[2]; lq1 = l8[3]; }
    else if (qq == 2) { lq0 = l8[4]; lq1 = l8[5]; }
    else              { lq0 = l8[6]; lq1 = l8[7]; }
    const float linv0 = 1.0f / (lq0 + 1e-16f);
    const float linv1 = 1.0f / (lq1 + 1e-16f);
    #pragma unroll
    for (int k = 0; k < 16; k++) acc[k] *= linv0;
    #pragma unroll
    for (int k = 16; k < 32; k++) acc[k] *= linv1;

    // butterfly-sum over the 16 candidate-slot lanes (xor bits 2..5)
    #pragma unroll
    for (int k = 0; k < 32; k++) {
        float v = acc[k];
        v += __shfl_xor(v, 4, 64);
        v += __shfl_xor(v, 8, 64);
        v += __shfl_xor(v, 16, 64);
        v += __shfl_xor(v, 32, 64);
        acc[k] = v;
    }
    if (cq == 0) {   // lanes 0..3; lane qq writes dims qq*32..qq*32+31 (h, pre-W_out)
        float4* orow = (float4*)(outH + (size_t)i * HID + qq * 32);
        #pragma unroll
        for (int s = 0; s < 8; s++)
            orow[s] = make_float4(acc[s * 4 + 0], acc[s * 4 + 1],
                                  acc[s * 4 + 2], acc[s * 4 + 3]);
    }
}

// ------- out = h @ W_out + b_out, in-place on outH (each block owns its rows) --
__global__ __launch_bounds__(256) void out_gemm_kernel(
    const float* __restrict__ Wout, const float* __restrict__ bout,
    float* __restrict__ outH)
{
    __shared__ __align__(16) float hsT[32][HID];   // 16 KB
    const int tid = threadIdx.x;
    const int r0 = blockIdx.x * 32;

    // stage this block's 32x128 h tile (coalesced float4), then it's safe to
    // overwrite those same rows
    for (int e = tid; e < 32 * 32; e += 256) {
        const int r = e >> 5, c4 = e & 31;
        ((float4*)&hsT[r][0])[c4] = ((const float4*)&outH[(size_t)(r0 + r) * HID])[c4];
    }
    __syncthreads();

    const int c = tid & 127;     // output column
    const int mg = tid >> 7;     // row group: rows mg*16 .. mg*16+15
    float acc[16];
    const float bb = bout[c];
    #pragma unroll
    for (int m = 0; m < 16; m++) acc[m] = bb;

    for (int k = 0; k < HID; k += 4) {
        const float w0 = Wout[(size_t)(k + 0) * HID + c];
        const float w1 = Wout[(size_t)(k + 1) * HID + c];
        const float w2 = Wout[(size_t)(k + 2) * HID + c];
        const float w3 = Wout[(size_t)(k + 3) * HID + c];
        #pragma unroll
        for (int m = 0; m < 16; m++) {
            const float4 hv = *(const float4*)&hsT[mg * 16 + m][k];
            acc[m] = fmaf(hv.x, w0, fmaf(hv.y, w1, fmaf(hv.z, w2, fmaf(hv.w, w3, acc[m]))));
        }
    }
    #pragma unroll
    for (int m = 0; m < 16; m++)
        outH[(size_t)(r0 + mg * 16 + m) * HID + c] = acc[m];
}

// ---------------- launch --------------------------------------------------------
extern "C" void kernel_launch(void* const* d_in, const int* in_sizes, int n_in,
                              void* d_out, int out_size, void* d_ws, size_t ws_size,
                              hipStream_t stream) {
    const float* Q    = (const float*)d_in[0];
    const float* Kx   = (const float*)d_in[1];
    const float* Vx   = (const float*)d_in[2];
    const float* lap  = (const float*)d_in[3];
    const float* Wq1  = (const float*)d_in[4];
    const float* bq1  = (const float*)d_in[5];
    const float* Wq2  = (const float*)d_in[6];
    const float* bq2  = (const float*)d_in[7];
    const float* Wk1  = (const float*)d_in[8];
    const float* bk1  = (const float*)d_in[9];
    const float* Wk2  = (const float*)d_in[10];
    const float* bk2  = (const float*)d_in[11];
    const float* spdb = (const float*)d_in[12];
    const float* dse  = (const float*)d_in[13];
    const float* dde  = (const float*)d_in[14];
    const float* Wout = (const float*)d_in[15];
    const float* bout = (const float*)d_in[16];
    const float* bndr = (const float*)d_in[17];
    const int*   ei   = (const int*)d_in[18];
    const int*   deg  = (const int*)d_in[19];

    float* out   = (float*)d_out;
    float* outH  = out;
    float* outLq = out + (size_t)NN * HID;
    float* outLk = outLq + (size_t)NN * NB;

    // workspace: ~1.86 MB total
    int* wsp = (int*)d_ws;
    size_t o = 0;
    auto carve = [&](size_t n_ints) -> int* {
        int* p = wsp + o; o += n_ints; return p;
    };
    int* bcnt  = carve(NB);
    int* boff  = carve(NB + 1);
    int* bfill = carve(NB);
    int* blist = carve(NN);
    int* bqv   = carve(NN);
    int* bkv   = carve(NN);
    int* ecnt  = carve(NN);      // reused as kept-adjacency count after dedup
    int* eoff  = carve(NN + 1);
    int* efill = carve(NN);
    int* adj   = carve(NE);
    int* qlist = carve(NN);

    zero_kernel<<<(NB + 255) / 256, 256, 0, stream>>>(bcnt, NB);
    zero_kernel<<<(NN + 255) / 256, 256, 0, stream>>>(ecnt, NN);

    mlp_kernel<<<NN / 16, 256, 0, stream>>>(Q,  lap, Wq1, bq1, Wq2, bq2, outLq, bqv);
    mlp_kernel<<<NN / 16, 256, 0, stream>>>(Kx, lap, Wk1, bk1, Wk2, bk2, outLk, bkv);

    // K-side bucket lists (candidate sets)
    hist_kernel<<<(NN + 255) / 256, 256, 0, stream>>>(bkv, bcnt);
    scan_bucket_kernel<<<1, 1024, 0, stream>>>(bcnt, boff, bfill);
    scatter_bucket_kernel<<<(NN + 255) / 256, 256, 0, stream>>>(bkv, bfill, blist);

    // Q-side ordering: longest-job-first (nodes of biggest K-buckets first)
    zero_kernel<<<(NB + 255) / 256, 256, 0, stream>>>(bcnt, NB);
    hist_kernel<<<(NN + 255) / 256, 256, 0, stream>>>(bqv, bcnt);
    order_kernel<<<1, 1024, 0, stream>>>(boff, bcnt, bfill);
    scatter_bucket_kernel<<<(NN + 255) / 256, 256, 0, stream>>>(bqv, bfill, qlist);

    // adjacency CSR
    edge_count_kernel<<<(NE + 255) / 256, 256, 0, stream>>>(ei, ecnt);
    scan_edge_kernel<<<1, 1024, 0, stream>>>(ecnt, eoff, efill);
    edge_scatter_kernel<<<(NE + 255) / 256, 256, 0, stream>>>(ei, efill, adj);

    // hoist dup/bucket filtering out of the hot loop
    dedup_kernel<<<NN / 4, 256, 0, stream>>>(eoff, adj, bqv, bkv, ecnt);

    attn_kernel<<<NN / 4, 256, 0, stream>>>(Q, Kx, Vx, lap, spdb, dse, dde, bndr, deg,
                                            bqv, boff, blist, eoff, ecnt, adj, qlist,
                                            outH);

    out_gemm_kernel<<<NN / 32, 256, 0, stream>>>(Wout, bout, outH);
}

// Round 6
// 823.185 us; speedup vs baseline: 1.2425x; 1.0110x over previous
//
#include <hip/hip_runtime.h>
#include <math.h>

#define NN 20000
#define HID 128
#define NH 8
#define HD 16
#define LAPD 16
#define NB 1024
#define NBINS 32
#define MAXDEG 64
#define NE 320000
#define DIN 144
#define NW 8          // waves per attn block
#define THRESH 512    // Ltot above this -> 8-way split across the block's waves

// finite "minus infinity" sentinel: never produces inf/NaN arithmetic,
// exp(x - NEGH) underflows to 0 in hardware. Real scores are |s| < ~1e4.
#define NEGH (-1.0e30f)

// ---------------- MLP: l = relu([X,lap]@W1+b1)@W2+b2, argmax over 1024 (fp32) ---
__global__ __launch_bounds__(256) void mlp_kernel(
    const float* __restrict__ X, const float* __restrict__ lap,
    const float* __restrict__ W1, const float* __restrict__ b1,
    const float* __restrict__ W2, const float* __restrict__ b2,
    float* __restrict__ outL, int* __restrict__ bidx)
{
    __shared__ __align__(16) float xs[16][DIN];
    __shared__ __align__(16) float hs[16][HID];
    __shared__ float rbv[64];
    __shared__ int   rbi[64];
    const int tid = threadIdx.x;
    const int n0 = blockIdx.x * 16;

    for (int e = tid; e < 16 * DIN; e += 256) {
        int n = e / DIN, k = e - n * DIN;
        float v = (k < HID) ? X[(size_t)(n0 + n) * HID + k]
                            : lap[(size_t)(n0 + n) * LAPD + (k - HID)];
        xs[n][k] = v;
    }
    __syncthreads();

    const int c = tid & 127, ng = tid >> 7;
    float hacc[8];
    {
        float bb = b1[c];
        #pragma unroll
        for (int m = 0; m < 8; m++) hacc[m] = bb;
        for (int k = 0; k < DIN; k += 4) {
            float w0 = W1[(k + 0) * HID + c];
            float w1 = W1[(k + 1) * HID + c];
            float w2 = W1[(k + 2) * HID + c];
            float w3 = W1[(k + 3) * HID + c];
            #pragma unroll
            for (int m = 0; m < 8; m++) {
                float4 xv = *(const float4*)&xs[ng * 8 + m][k];
                hacc[m] = fmaf(xv.x, w0, hacc[m]);
                hacc[m] = fmaf(xv.y, w1, hacc[m]);
                hacc[m] = fmaf(xv.z, w2, hacc[m]);
                hacc[m] = fmaf(xv.w, w3, hacc[m]);
            }
        }
    }
    #pragma unroll
    for (int m = 0; m < 8; m++) hs[ng * 8 + m][c] = fmaxf(hacc[m], 0.0f);
    __syncthreads();

    float a0[16], a1[16], a2[16], a3[16];
    #pragma unroll
    for (int m = 0; m < 16; m++) { a0[m] = 0.f; a1[m] = 0.f; a2[m] = 0.f; a3[m] = 0.f; }

    // software-pipelined W2 loads
    const float* W2b = W2 + 4 * tid;
    float4 w0 = *(const float4*)&W2b[(size_t)0 * NB];
    float4 w1 = *(const float4*)&W2b[(size_t)1 * NB];
    float4 w2 = *(const float4*)&W2b[(size_t)2 * NB];
    float4 w3 = *(const float4*)&W2b[(size_t)3 * NB];
    for (int k = 0; k < HID; k += 4) {
        const int kn = (k + 4 < HID) ? (k + 4) : 0;   // clamp: harmless hot reload
        float4 nw0 = *(const float4*)&W2b[(size_t)(kn + 0) * NB];
        float4 nw1 = *(const float4*)&W2b[(size_t)(kn + 1) * NB];
        float4 nw2 = *(const float4*)&W2b[(size_t)(kn + 2) * NB];
        float4 nw3 = *(const float4*)&W2b[(size_t)(kn + 3) * NB];
        #pragma unroll
        for (int m = 0; m < 16; m++) {
            const float4 hv = *(const float4*)&hs[m][k];
            a0[m] = fmaf(hv.x, w0.x, fmaf(hv.y, w1.x, fmaf(hv.z, w2.x, fmaf(hv.w, w3.x, a0[m]))));
            a1[m] = fmaf(hv.x, w0.y, fmaf(hv.y, w1.y, fmaf(hv.z, w2.y, fmaf(hv.w, w3.y, a1[m]))));
            a2[m] = fmaf(hv.x, w0.z, fmaf(hv.y, w1.z, fmaf(hv.z, w2.z, fmaf(hv.w, w3.z, a2[m]))));
            a3[m] = fmaf(hv.x, w0.w, fmaf(hv.y, w1.w, fmaf(hv.z, w2.w, fmaf(hv.w, w3.w, a3[m]))));
        }
        w0 = nw0; w1 = nw1; w2 = nw2; w3 = nw3;
    }

    const float4 bb4 = *(const float4*)&b2[4 * tid];
    const int lane = tid & 63, wv = tid >> 6;
    const int o0 = 4 * tid;
    for (int m = 0; m < 16; m++) {
        float4 ov;
        ov.x = a0[m] + bb4.x; ov.y = a1[m] + bb4.y;
        ov.z = a2[m] + bb4.z; ov.w = a3[m] + bb4.w;
        *(float4*)&outL[(size_t)(n0 + m) * NB + o0] = ov;
        float bv = ov.x; int bi = o0;
        if (ov.y > bv) { bv = ov.y; bi = o0 + 1; }
        if (ov.z > bv) { bv = ov.z; bi = o0 + 2; }
        if (ov.w > bv) { bv = ov.w; bi = o0 + 3; }
        #pragma unroll
        for (int off = 1; off < 64; off <<= 1) {
            float ovv = __shfl_xor(bv, off, 64);
            int   oi  = __shfl_xor(bi, off, 64);
            if (ovv > bv || (ovv == bv && oi < bi)) { bv = ovv; bi = oi; }
        }
        if (lane == 0) { rbv[wv * 16 + m] = bv; rbi[wv * 16 + m] = bi; }
    }
    __syncthreads();
    if (tid < 16) {
        float bv = rbv[tid]; int bi = rbi[tid];
        #pragma unroll
        for (int ww = 1; ww < 4; ww++) {
            float ov = rbv[ww * 16 + tid]; int oi = rbi[ww * 16 + tid];
            if (ov > bv || (ov == bv && oi < bi)) { bv = ov; bi = oi; }
        }
        bidx[n0 + tid] = min(max(bi, 0), NB - 1);
    }
}

// ---------------- small utility kernels ----------------------------------------
__global__ void zero_kernel(int* __restrict__ p, int n) {
    int i = blockIdx.x * 256 + threadIdx.x;
    if (i < n) p[i] = 0;
}

__global__ void hist_kernel(const int* __restrict__ bkarr, int* __restrict__ bcnt) {
    int i = blockIdx.x * 256 + threadIdx.x;
    if (i < NN) {
        int b = min(max(bkarr[i], 0), NB - 1);
        atomicAdd(&bcnt[b], 1);
    }
}

__global__ __launch_bounds__(1024) void scan_bucket_kernel(const int* __restrict__ cnt,
        int* __restrict__ off, int* __restrict__ fill) {
    __shared__ int s[1024];
    int t = threadIdx.x;
    int v = cnt[t];
    s[t] = v; __syncthreads();
    for (int o = 1; o < 1024; o <<= 1) {
        int a = (t >= o) ? s[t - o] : 0;
        __syncthreads();
        s[t] += a;
        __syncthreads();
    }
    int excl = s[t] - v;
    off[t] = excl; fill[t] = excl;
    if (t == 1023) off[NB] = s[1023];
}

// ------- longest-job-first ordering: sort buckets by K-side size descending
__global__ __launch_bounds__(1024) void order_kernel(
    const int* __restrict__ boff,    // K-side bucket offsets (kcnt = diff)
    const int* __restrict__ qcnt,    // Q-side bucket counts
    int* __restrict__ qfill)         // out: per-bucket scatter base
{
    __shared__ int kk[1024];
    __shared__ int ii[1024];
    __shared__ int ss[1024];
    const int t = threadIdx.x;
    kk[t] = boff[t + 1] - boff[t];
    ii[t] = t;
    __syncthreads();
    for (int size = 2; size <= 1024; size <<= 1) {
        for (int stride = size >> 1; stride > 0; stride >>= 1) {
            const int p = t ^ stride;
            if (p > t) {
                const int k1 = kk[t], k2 = kk[p];
                const bool up = ((t & size) == 0);
                if ((k1 < k2) == up) {
                    const int i1 = ii[t];
                    kk[t] = k2; kk[p] = k1;
                    ii[t] = ii[p]; ii[p] = i1;
                }
            }
            __syncthreads();
        }
    }
    const int v = qcnt[ii[t]];
    ss[t] = v; __syncthreads();
    for (int o = 1; o < 1024; o <<= 1) {
        int a = (t >= o) ? ss[t - o] : 0;
        __syncthreads();
        ss[t] += a;
        __syncthreads();
    }
    qfill[ii[t]] = ss[t] - v;
}

__global__ void scatter_bucket_kernel(const int* __restrict__ bkarr,
        int* __restrict__ fill, int* __restrict__ blist) {
    int i = blockIdx.x * 256 + threadIdx.x;
    if (i < NN) {
        int b = min(max(bkarr[i], 0), NB - 1);
        int p = atomicAdd(&fill[b], 1);
        if (p >= 0 && p < NN) blist[p] = i;
    }
}

__global__ __launch_bounds__(1024) void scan_edge_kernel(const int* __restrict__ cnt,
        int* __restrict__ off, int* __restrict__ fill) {
    __shared__ int s[1024];
    const int t = threadIdx.x;
    const int base = t * 20;   // 1024*20 >= 20000
    int loc[20]; int sum = 0;
    #pragma unroll
    for (int k = 0; k < 20; k++) {
        int idx = base + k;
        int v = (idx < NN) ? cnt[idx] : 0;
        loc[k] = sum; sum += v;
    }
    s[t] = sum; __syncthreads();
    for (int o = 1; o < 1024; o <<= 1) {
        int a = (t >= o) ? s[t - o] : 0;
        __syncthreads();
        s[t] += a;
        __syncthreads();
    }
    int pre = s[t] - sum;
    #pragma unroll
    for (int k = 0; k < 20; k++) {
        int idx = base + k;
        if (idx < NN) { int e = pre + loc[k]; off[idx] = e; fill[idx] = e; }
    }
    if (t == 1023) off[NN] = s[1023];
}

__global__ void edge_count_kernel(const int* __restrict__ ei, int* __restrict__ ecnt) {
    int e = blockIdx.x * 256 + threadIdx.x;
    if (e < NE) {
        int s = min(max(ei[e], 0), NN - 1);
        atomicAdd(&ecnt[s], 1);
    }
}

__global__ void edge_scatter_kernel(const int* __restrict__ ei,
        int* __restrict__ fill, int* __restrict__ adj) {
    int e = blockIdx.x * 256 + threadIdx.x;
    if (e < NE) {
        int s = min(max(ei[e], 0), NN - 1);
        int d = min(max(ei[NE + e], 0), NN - 1);
        int p = atomicAdd(&fill[s], 1);
        if (p >= 0 && p < NE) adj[p] = d;
    }
}

// ------- adjacency clean-up (off the hot path) ---------------------------------
__global__ __launch_bounds__(256) void dedup_kernel(
    const int* __restrict__ eoff, int* __restrict__ adj,
    const int* __restrict__ bqv, const int* __restrict__ bkv,
    int* __restrict__ acnt)
{
    __shared__ int prev[4][192];
    const int lane = threadIdx.x & 63, wv = threadIdx.x >> 6;
    const int i = blockIdx.x * 4 + wv;
    if (i >= NN) return;
    int es = eoff[i], ee = eoff[i + 1];
    es = min(max(es, 0), NE); ee = min(max(ee, es), NE);
    const int d = ee - es;
    const int b = min(max(bqv[i], 0), NB - 1);
    int kept = 0;
    for (int t0 = 0; t0 < d; t0 += 64) {
        const int t = t0 + lane;
        const bool in = t < d;
        int j = -1;
        if (in) j = min(max(adj[es + t], 0), NN - 1);
        bool keep = in && ((j == i) || (bkv[j] != b));
        const int nin = min(64, d - t0);
        for (int q2 = 0; q2 < nin; q2++) {
            int jq = __shfl(j, q2, 64);
            if (in && q2 < lane && jq == j) keep = false;
        }
        if (t0 > 0 && in) {
            asm volatile("s_waitcnt lgkmcnt(0)" ::: "memory");
            const int np = min(t0, 192);
            for (int q2 = 0; q2 < np; q2++)
                if (prev[wv][q2] == j) keep = false;
        }
        if (in && t < 192) prev[wv][t] = j;   // record ORIGINAL value before compaction
        unsigned long long km = __ballot(keep);
        int pos = __popcll(km & ((1ull << lane) - 1ull));
        if (keep) adj[es + kept + pos] = j;   // write idx <= read idx: in-place safe
        kept += (int)__popcll(km);
    }
    if (lane == 0) acnt[i] = kept;
}

// ------- stable partition of the LJF qlist into big (Ltot>THRESH) / small -----
// smalls_before(p) = p - bigs_before(p), so ONE scan suffices.
__global__ __launch_bounds__(1024) void partition_kernel(
    const int* __restrict__ qlist, const int* __restrict__ bqv,
    const int* __restrict__ boff, const int* __restrict__ acnt,
    int* __restrict__ biglist, int* __restrict__ smalllist, int* __restrict__ cnts)
{
    __shared__ int s[1024];
    const int t = threadIdx.x;
    const int base = t * 20;
    int loc[20], nid[20], flg[20];
    int sum = 0;
    #pragma unroll
    for (int k = 0; k < 20; k++) {
        const int p = base + k;
        int big = 0, n = 0;
        if (p < NN) {
            n = min(max(qlist[p], 0), NN - 1);
            const int b = min(max(bqv[n], 0), NB - 1);
            const int L = (boff[b + 1] - boff[b]) + min(max(acnt[n], 0), NE);
            big = (L > THRESH) ? 1 : 0;
        }
        nid[k] = n; flg[k] = big;
        loc[k] = sum; sum += big;
    }
    s[t] = sum; __syncthreads();
    for (int o = 1; o < 1024; o <<= 1) {
        int a = (t >= o) ? s[t - o] : 0;
        __syncthreads();
        s[t] += a;
        __syncthreads();
    }
    const int pre = s[t] - sum;
    #pragma unroll
    for (int k = 0; k < 20; k++) {
        const int p = base + k;
        if (p < NN) {
            const int bb = pre + loc[k];          // bigs before p
            if (flg[k]) biglist[bb] = nid[k];
            else        smalllist[p - bb] = nid[k];
        }
    }
    if (t == 1023) cnts[0] = s[1023];
}

// ------- attention: 512-thread blocks (8 waves) --------------------------------
// blocks [0,nbig): ONE big node, candidate range split into 8 segments (one per
//   wave), online-softmax partials merged in LDS (flash-decoding style).
// blocks [nbig, ...): 8 small nodes per block, one per wave (previous path).
// Phase A candidate-major; phase B quad-split PV (lane cq=slot, qq=dim-quarter).
// Writes NORMALIZED h to outH; out_gemm applies W_out afterward.
__global__ __launch_bounds__(512) void attn_kernel(
    const float* __restrict__ Q, const float* __restrict__ K, const float* __restrict__ V,
    const float* __restrict__ lap,
    const float* __restrict__ spdb, const float* __restrict__ dse,
    const float* __restrict__ dde, const float* __restrict__ bndr,
    const int* __restrict__ deg,
    const int* __restrict__ bq,
    const int* __restrict__ boff, const int* __restrict__ blist,
    const int* __restrict__ eoff, const int* __restrict__ acnt,
    const int* __restrict__ adj,
    const int* __restrict__ biglist, const int* __restrict__ smalllist,
    const int* __restrict__ cnts,
    float* __restrict__ outH)
{
    __shared__ __align__(16) float qfl[NW][128];
    __shared__ __align__(16) float pefl[NW][16];
    __shared__ float wts[NW][8][66];
    __shared__ int   jls[NW][64];
    __shared__ __align__(16) float spdbs[(NBINS + 1) * NH];   // 264
    __shared__ __align__(16) float ddes[(MAXDEG + 2) * NH];   // 528
    __shared__ float bnd[32];
    __shared__ float mrgm[NW][8], mrgl[NW][8];
    __shared__ float hpart[NW][128];
    __shared__ float ltot_s[8];

    const int tid = threadIdx.x;
    const int wv = tid >> 6, lane = tid & 63;
    const int cq = lane >> 2, qq = lane & 3;   // candidate slot / dim-quarter

    int nbig = min(max(cnts[0], 0), NN);
    const int nsmall = NN - nbig;
    const int nblocks = nbig + (nsmall + NW - 1) / NW;
    const int br = (int)blockIdx.x;
    if (br >= nblocks) return;

    const bool bigm = (br < nbig);
    bool active = true;
    int i;
    if (bigm) {
        i = biglist[br];
    } else {
        const int task = (br - nbig) * NW + wv;
        active = (task < nsmall);
        i = active ? smalllist[task] : 0;
    }
    i = min(max(i, 0), NN - 1);

    for (int e = tid; e < (NBINS + 1) * NH; e += 512) spdbs[e] = spdb[e];
    for (int e = tid; e < (MAXDEG + 2) * NH; e += 512) ddes[e] = dde[e];
    if (tid < 32) bnd[tid] = bndr[tid];
    qfl[wv][lane]      = Q[(size_t)i * HID + lane];
    qfl[wv][lane + 64] = Q[(size_t)i * HID + 64 + lane];
    if (lane < 16) pefl[wv][lane] = lap[(size_t)i * LAPD + lane];

    int b = min(max(bq[i], 0), NB - 1);
    int bs = boff[b], be = boff[b + 1];
    bs = min(max(bs, 0), NN); be = min(max(be, bs), NN);
    int es = eoff[i];
    es = min(max(es, 0), NE);
    int na = min(max(acnt[i], 0), NE - es);
    const int Lb = be - bs;
    const int Ltot = Lb + na;
    const int degi = min(max(deg[i], 0), MAXDEG + 1);

    // per-wave candidate range [tb, te)
    int tb = 0, te = Ltot;
    if (bigm) {
        const int Lseg = (Ltot + NW - 1) / NW;
        tb = min(wv * Lseg, Ltot);
        te = min(tb + Lseg, Ltot);
    }
    if (!active) { tb = 0; te = 0; }

    // prefetch first chunk's candidate index (overlaps the staging barrier)
    int jn = i; bool vn = false;
    {
        const int t = tb + lane;
        if (t < te) {
            if (t < Lb) {
                jn = min(max(blist[bs + t], 0), NN - 1);
                vn = (jn != i);
            } else {
                jn = min(max(adj[es + (t - Lb)], 0), NN - 1);
                vn = true;   // pre-deduped, pre-filtered
            }
        }
    }
    __syncthreads();   // tables + per-wave staging visible

    const float4 ds0 = *(const float4*)&dse[degi * 8];
    const float4 ds1 = *(const float4*)&dse[degi * 8 + 4];

    float m8[8], l8[8];
    #pragma unroll
    for (int h = 0; h < 8; h++) { m8[h] = NEGH; l8[h] = 0.0f; }
    float acc[32];
    #pragma unroll
    for (int k = 0; k < 32; k++) acc[k] = 0.0f;

    for (int t0 = tb; t0 < te; t0 += 64) {
        const int j = jn; const bool valid = vn;

        // ---- phase A: candidate-major scores ----
        float s8[8];
        if (valid) {
            const float4* K4 = (const float4*)(K + (size_t)j * HID);
            const float4* Q4 = (const float4*)&qfl[wv][0];
            #pragma unroll
            for (int h = 0; h < 8; h++) {
                float4 k0 = K4[h * 4 + 0], k1 = K4[h * 4 + 1];
                float4 k2 = K4[h * 4 + 2], k3 = K4[h * 4 + 3];
                float4 q0 = Q4[h * 4 + 0], q1 = Q4[h * 4 + 1];
                float4 q2 = Q4[h * 4 + 2], q3 = Q4[h * 4 + 3];
                float dot = 0.0f;
                dot = fmaf(q0.x, k0.x, dot); dot = fmaf(q0.y, k0.y, dot);
                dot = fmaf(q0.z, k0.z, dot); dot = fmaf(q0.w, k0.w, dot);
                dot = fmaf(q1.x, k1.x, dot); dot = fmaf(q1.y, k1.y, dot);
                dot = fmaf(q1.z, k1.z, dot); dot = fmaf(q1.w, k1.w, dot);
                dot = fmaf(q2.x, k2.x, dot); dot = fmaf(q2.y, k2.y, dot);
                dot = fmaf(q2.z, k2.z, dot); dot = fmaf(q2.w, k2.w, dot);
                dot = fmaf(q3.x, k3.x, dot); dot = fmaf(q3.y, k3.y, dot);
                dot = fmaf(q3.z, k3.z, dot); dot = fmaf(q3.w, k3.w, dot);
                s8[h] = dot * 0.25f;   // /sqrt(16)
            }
            const float4* P4 = (const float4*)&pefl[wv][0];
            const float4* L4 = (const float4*)(lap + (size_t)j * LAPD);
            float ss = 0.0f;
            #pragma unroll
            for (int d4 = 0; d4 < 4; d4++) {
                float4 pe = P4[d4], lj = L4[d4];
                float dx = pe.x - lj.x, dy = pe.y - lj.y;
                float dz = pe.z - lj.z, dw = pe.w - lj.w;
                ss = fmaf(dx, dx, ss); ss = fmaf(dy, dy, ss);
                ss = fmaf(dz, dz, ss); ss = fmaf(dw, dw, ss);
            }
            float dist = sqrtf(ss);
            int si = 0;
            #pragma unroll
            for (int kb = 0; kb < 32; kb++) si += (bnd[kb] < dist) ? 1 : 0;  // searchsorted left
            const int dj = min(max(deg[j], 0), MAXDEG + 1);
            const float4 sb0 = *(const float4*)&spdbs[si * 8];
            const float4 sb1 = *(const float4*)&spdbs[si * 8 + 4];
            const float4 db0 = *(const float4*)&ddes[dj * 8];
            const float4 db1 = *(const float4*)&ddes[dj * 8 + 4];
            s8[0] += sb0.x + ds0.x + db0.x; s8[1] += sb0.y + ds0.y + db0.y;
            s8[2] += sb0.z + ds0.z + db0.z; s8[3] += sb0.w + ds0.w + db0.w;
            s8[4] += sb1.x + ds1.x + db1.x; s8[5] += sb1.y + ds1.y + db1.y;
            s8[6] += sb1.z + ds1.z + db1.z; s8[7] += sb1.w + ds1.w + db1.w;
        } else {
            #pragma unroll
            for (int h = 0; h < 8; h++) s8[h] = NEGH;
        }
        jls[wv][lane] = valid ? j : i;

        // prefetch next chunk's candidate index (latency hidden under phase B)
        jn = i; vn = false;
        {
            const int t2 = t0 + 64 + lane;
            if (t2 < te) {
                if (t2 < Lb) {
                    jn = min(max(blist[bs + t2], 0), NN - 1);
                    vn = (jn != i);
                } else {
                    jn = min(max(adj[es + (t2 - Lb)], 0), NN - 1);
                    vn = true;
                }
            }
        }

        // ---- softmax bookkeeping (m wave-uniform, l per-lane partial) ----
        float alpha8[8];
        #pragma unroll
        for (int h = 0; h < 8; h++) {
            float cm = s8[h];
            #pragma unroll
            for (int off = 1; off < 64; off <<= 1)
                cm = fmaxf(cm, __shfl_xor(cm, off, 64));
            const float mn = fmaxf(m8[h], cm);
            alpha8[h] = __expf(m8[h] - mn);
            const float p = valid ? __expf(s8[h] - mn) : 0.0f;
            l8[h] = l8[h] * alpha8[h] + p;
            m8[h] = mn;
            wts[wv][h][lane] = p;
        }

        // alpha for this lane's two heads (compile-time indices per arm)
        float aq0, aq1;
        if (qq == 0)      { aq0 = alpha8[0]; aq1 = alpha8[1]; }
        else if (qq == 1) { aq0 = alpha8[2]; aq1 = alpha8[3]; }
        else if (qq == 2) { aq0 = alpha8[4]; aq1 = alpha8[5]; }
        else              { aq0 = alpha8[6]; aq1 = alpha8[7]; }

        #pragma unroll
        for (int k = 0; k < 16; k++) acc[k] *= aq0;
        #pragma unroll
        for (int k = 16; k < 32; k++) acc[k] *= aq1;

        // same-wave LDS handoff: drain DS writes before cross-lane reads
        asm volatile("s_waitcnt lgkmcnt(0)" ::: "memory");

        // ---- phase B: quad-split PV ----
        const int rem = te - t0;
        const int npass = ((rem < 64 ? rem : 64) + 15) >> 4;
        for (int r = 0; r < npass; r++) {
            const int cc = r * 16 + cq;
            const int jc = jls[wv][cc];
            const float w0 = wts[wv][2 * qq][cc];
            const float w1 = wts[wv][2 * qq + 1][cc];
            const float4* V4 = (const float4*)(V + (size_t)jc * HID + qq * 32);
            #pragma unroll
            for (int s = 0; s < 4; s++) {
                const float4 v = V4[s];
                acc[s * 4 + 0] = fmaf(w0, v.x, acc[s * 4 + 0]);
                acc[s * 4 + 1] = fmaf(w0, v.y, acc[s * 4 + 1]);
                acc[s * 4 + 2] = fmaf(w0, v.z, acc[s * 4 + 2]);
                acc[s * 4 + 3] = fmaf(w0, v.w, acc[s * 4 + 3]);
            }
            #pragma unroll
            for (int s = 4; s < 8; s++) {
                const float4 v = V4[s];
                acc[s * 4 + 0] = fmaf(w1, v.x, acc[s * 4 + 0]);
                acc[s * 4 + 1] = fmaf(w1, v.y, acc[s * 4 + 1]);
                acc[s * 4 + 2] = fmaf(w1, v.z, acc[s * 4 + 2]);
                acc[s * 4 + 3] = fmaf(w1, v.w, acc[s * 4 + 3]);
            }
        }
    }

    // ---- reduce l8 across wave (both modes) ----
    #pragma unroll
    for (int h = 0; h < 8; h++) {
        float v = l8[h];
        #pragma unroll
        for (int off = 1; off < 64; off <<= 1) v += __shfl_xor(v, off, 64);
        l8[h] = v;
    }

    if (bigm) {
        // ---- 8-way segment merge in LDS (flash-decoding) ----
        if (lane == 0) {
            #pragma unroll
            for (int h = 0; h < 8; h++) { mrgm[wv][h] = m8[h]; mrgl[wv][h] = l8[h]; }
        }
        __syncthreads();
        // this lane's two heads: ma_/mb_ from regs (compile-time index chain)
        float ma_, mb_;
        if (qq == 0)      { ma_ = m8[0]; mb_ = m8[1]; }
        else if (qq == 1) { ma_ = m8[2]; mb_ = m8[3]; }
        else if (qq == 2) { ma_ = m8[4]; mb_ = m8[5]; }
        else              { ma_ = m8[6]; mb_ = m8[7]; }
        float Ma = mrgm[0][2 * qq], Mb = mrgm[0][2 * qq + 1];
        #pragma unroll
        for (int w = 1; w < NW; w++) {
            Ma = fmaxf(Ma, mrgm[w][2 * qq]);
            Mb = fmaxf(Mb, mrgm[w][2 * qq + 1]);
        }
        const float fa = __expf(ma_ - Ma);
        const float fb = __expf(mb_ - Mb);
        #pragma unroll
        for (int k = 0; k < 16; k++) acc[k] *= fa;
        #pragma unroll
        for (int k = 16; k < 32; k++) acc[k] *= fb;
        // butterfly-sum over the 16 candidate-slot lanes
        #pragma unroll
        for (int k = 0; k < 32; k++) {
            float v = acc[k];
            v += __shfl_xor(v, 4, 64);
            v += __shfl_xor(v, 8, 64);
            v += __shfl_xor(v, 16, 64);
            v += __shfl_xor(v, 32, 64);
            acc[k] = v;
        }
        if (cq == 0) {
            #pragma unroll
            for (int k = 0; k < 32; k++) hpart[wv][qq * 32 + k] = acc[k];
        }
        if (tid < 8) {
            float M = mrgm[0][tid];
            #pragma unroll
            for (int w = 1; w < NW; w++) M = fmaxf(M, mrgm[w][tid]);
            float lt = 0.0f;
            #pragma unroll
            for (int w = 0; w < NW; w++) lt += mrgl[w][tid] * __expf(mrgm[w][tid] - M);
            ltot_s[tid] = lt;
        }
        __syncthreads();
        if (tid < 128) {
            float sum = hpart[0][tid];
            #pragma unroll
            for (int w = 1; w < NW; w++) sum += hpart[w][tid];
            outH[(size_t)i * HID + tid] = sum / (ltot_s[tid >> 4] + 1e-16f);
        }
    } else {
        // ---- small path: normalize in-wave, butterfly, write ----
        float lq0, lq1;
        if (qq == 0)      { lq0 = l8[0]; lq1 = l8[1]; }
        else if (qq == 1) { lq0 = l8[2]; lq1 = l8[3]; }
        else if (qq == 2) { lq0 = l8[4]; lq1 = l8[5]; }
        else              { lq0 = l8[6]; lq1 = l8[7]; }
        const float linv0 = 1.0f / (lq0 + 1e-16f);
        const float linv1 = 1.0f / (lq1 + 1e-16f);
        #pragma unroll
        for (int k = 0; k < 16; k++) acc[k] *= linv0;
        #pragma unroll
        for (int k = 16; k < 32; k++) acc[k] *= linv1;
        #pragma unroll
        for (int k = 0; k < 32; k++) {
            float v = acc[k];
            v += __shfl_xor(v, 4, 64);
            v += __shfl_xor(v, 8, 64);
            v += __shfl_xor(v, 16, 64);
            v += __shfl_xor(v, 32, 64);
            acc[k] = v;
        }
        if (active && cq == 0) {   // lanes 0..3; lane qq writes dims qq*32..qq*32+31
            float4* orow = (float4*)(outH + (size_t)i * HID + qq * 32);
            #pragma unroll
            for (int s = 0; s < 8; s++)
                orow[s] = make_float4(acc[s * 4 + 0], acc[s * 4 + 1],
                                      acc[s * 4 + 2], acc[s * 4 + 3]);
        }
    }
}

// ------- out = h @ W_out + b_out, in-place on outH (each block owns its rows) --
__global__ __launch_bounds__(256) void out_gemm_kernel(
    const float* __restrict__ Wout, const float* __restrict__ bout,
    float* __restrict__ outH)
{
    __shared__ __align__(16) float hsT[32][HID];   // 16 KB
    const int tid = threadIdx.x;
    const int r0 = blockIdx.x * 32;

    for (int e = tid; e < 32 * 32; e += 256) {
        const int r = e >> 5, c4 = e & 31;
        ((float4*)&hsT[r][0])[c4] = ((const float4*)&outH[(size_t)(r0 + r) * HID])[c4];
    }
    __syncthreads();

    const int c = tid & 127;     // output column
    const int mg = tid >> 7;     // row group: rows mg*16 .. mg*16+15
    float acc[16];
    const float bb = bout[c];
    #pragma unroll
    for (int m = 0; m < 16; m++) acc[m] = bb;

    for (int k = 0; k < HID; k += 4) {
        const float w0 = Wout[(size_t)(k + 0) * HID + c];
        const float w1 = Wout[(size_t)(k + 1) * HID + c];
        const float w2 = Wout[(size_t)(k + 2) * HID + c];
        const float w3 = Wout[(size_t)(k + 3) * HID + c];
        #pragma unroll
        for (int m = 0; m < 16; m++) {
            const float4 hv = *(const float4*)&hsT[mg * 16 + m][k];
            acc[m] = fmaf(hv.x, w0, fmaf(hv.y, w1, fmaf(hv.z, w2, fmaf(hv.w, w3, acc[m]))));
        }
    }
    #pragma unroll
    for (int m = 0; m < 16; m++)
        outH[(size_t)(r0 + mg * 16 + m) * HID + c] = acc[m];
}

// ---------------- launch --------------------------------------------------------
extern "C" void kernel_launch(void* const* d_in, const int* in_sizes, int n_in,
                              void* d_out, int out_size, void* d_ws, size_t ws_size,
                              hipStream_t stream) {
    const float* Q    = (const float*)d_in[0];
    const float* Kx   = (const float*)d_in[1];
    const float* Vx   = (const float*)d_in[2];
    const float* lap  = (const float*)d_in[3];
    const float* Wq1  = (const float*)d_in[4];
    const float* bq1  = (const float*)d_in[5];
    const float* Wq2  = (const float*)d_in[6];
    const float* bq2  = (const float*)d_in[7];
    const float* Wk1  = (const float*)d_in[8];
    const float* bk1  = (const float*)d_in[9];
    const float* Wk2  = (const float*)d_in[10];
    const float* bk2  = (const float*)d_in[11];
    const float* spdb = (const float*)d_in[12];
    const float* dse  = (const float*)d_in[13];
    const float* dde  = (const float*)d_in[14];
    const float* Wout = (const float*)d_in[15];
    const float* bout = (const float*)d_in[16];
    const float* bndr = (const float*)d_in[17];
    const int*   ei   = (const int*)d_in[18];
    const int*   deg  = (const int*)d_in[19];

    float* out   = (float*)d_out;
    float* outH  = out;
    float* outLq = out + (size_t)NN * HID;
    float* outLk = outLq + (size_t)NN * NB;

    // workspace: ~2.0 MB total
    int* wsp = (int*)d_ws;
    size_t o = 0;
    auto carve = [&](size_t n_ints) -> int* {
        int* p = wsp + o; o += n_ints; return p;
    };
    int* bcnt   = carve(NB);
    int* boff   = carve(NB + 1);
    int* bfill  = carve(NB);
    int* blist  = carve(NN);
    int* bqv    = carve(NN);
    int* bkv    = carve(NN);
    int* ecnt   = carve(NN);     // reused as kept-adjacency count after dedup
    int* eoff   = carve(NN + 1);
    int* efill  = carve(NN);
    int* adj    = carve(NE);
    int* qlist  = carve(NN);
    int* biglist   = carve(NN);
    int* smalllist = carve(NN);
    int* cnts   = carve(4);

    zero_kernel<<<(NB + 255) / 256, 256, 0, stream>>>(bcnt, NB);
    zero_kernel<<<(NN + 255) / 256, 256, 0, stream>>>(ecnt, NN);

    mlp_kernel<<<NN / 16, 256, 0, stream>>>(Q,  lap, Wq1, bq1, Wq2, bq2, outLq, bqv);
    mlp_kernel<<<NN / 16, 256, 0, stream>>>(Kx, lap, Wk1, bk1, Wk2, bk2, outLk, bkv);

    // K-side bucket lists (candidate sets)
    hist_kernel<<<(NN + 255) / 256, 256, 0, stream>>>(bkv, bcnt);
    scan_bucket_kernel<<<1, 1024, 0, stream>>>(bcnt, boff, bfill);
    scatter_bucket_kernel<<<(NN + 255) / 256, 256, 0, stream>>>(bkv, bfill, blist);

    // Q-side ordering: longest-job-first (nodes of biggest K-buckets first)
    zero_kernel<<<(NB + 255) / 256, 256, 0, stream>>>(bcnt, NB);
    hist_kernel<<<(NN + 255) / 256, 256, 0, stream>>>(bqv, bcnt);
    order_kernel<<<1, 1024, 0, stream>>>(boff, bcnt, bfill);
    scatter_bucket_kernel<<<(NN + 255) / 256, 256, 0, stream>>>(bqv, bfill, qlist);

    // adjacency CSR
    edge_count_kernel<<<(NE + 255) / 256, 256, 0, stream>>>(ei, ecnt);
    scan_edge_kernel<<<1, 1024, 0, stream>>>(ecnt, eoff, efill);
    edge_scatter_kernel<<<(NE + 255) / 256, 256, 0, stream>>>(ei, efill, adj);

    // hoist dup/bucket filtering out of the hot loop
    dedup_kernel<<<NN / 4, 256, 0, stream>>>(eoff, adj, bqv, bkv, ecnt);

    // split heavy nodes (Ltot > THRESH) for 8-way intra-node parallelism
    partition_kernel<<<1, 1024, 0, stream>>>(qlist, bqv, boff, ecnt,
                                             biglist, smalllist, cnts);

    // grid = NN covers the worst case (all nodes big); excess blocks early-exit
    attn_kernel<<<NN, 512, 0, stream>>>(Q, Kx, Vx, lap, spdb, dse, dde, bndr, deg,
                                        bqv, boff, blist, eoff, ecnt, adj,
                                        biglist, smalllist, cnts, outH);

    out_gemm_kernel<<<NN / 32, 256, 0, stream>>>(Wout, bout, outH);
}